// Round 1
// baseline (15966.748 us; speedup 1.0000x reference)
//
#include <hip/hip_runtime.h>
#include <math.h>

// Problem constants
constexpr int NV = 32000, ND = 1024, NH = 16, NHD = 64, NL = 3, NDFF = 4096;
constexpr int NE = 8, NB = 2, NS = 1024, NT = NB * NS;

// ---------------------------------------------------------------------------
// YaRN cos/sin table: c[s*32+j], sn[s*32+j]  (half table, d%32 indexing)
// low=floor(corr_dim(32))=8, high=min(ceil(corr_dim(1)),63)=21, mscale=0.1*ln(8)+1
__global__ void yarn_kernel(float* __restrict__ c, float* __restrict__ sn) {
    int idx = blockIdx.x * blockDim.x + threadIdx.x;   // NS*32 threads
    int j = idx & 31;
    int s = idx >> 5;
    double ex = (double)(2 * j) / 64.0;
    double fe = 1.0 / pow(10000.0, ex);
    double fi = fe / 8.0;
    double lin = ((double)j - 8.0) / 13.0;
    double mask = 1.0 - fmin(fmax(lin, 0.0), 1.0);
    double invf = fi * (1.0 - mask) + fe * mask;
    double ms = 0.1 * log(8.0) + 1.0;
    double fr = (double)s * invf;
    c[idx]  = (float)(cos(fr) * ms);
    sn[idx] = (float)(sin(fr) * ms);
}

// ---------------------------------------------------------------------------
__global__ void embed_kernel(const int* __restrict__ src, const float* __restrict__ emb,
                             float* __restrict__ x) {
    int idx = blockIdx.x * blockDim.x + threadIdx.x;   // NT*ND threads
    int t = idx >> 10;
    int d = idx & 1023;
    int s = src[t];
    s = s < 0 ? 0 : (s > NV - 1 ? NV - 1 : s);
    x[idx] = emb[(size_t)s * ND + d] * 32.0f;          // sqrt(1024)=32
}

// ---------------------------------------------------------------------------
// RoPE in-place on q and k. Layout [T, H*HD]; head h at cols h*64..h*64+63.
__global__ void rope_kernel(float* __restrict__ q, float* __restrict__ k,
                            const float* __restrict__ c, const float* __restrict__ sn) {
    int idx = blockIdx.x * blockDim.x + threadIdx.x;   // NT*NH*32 threads
    int j = idx & 31;
    int h = (idx >> 5) & 15;
    int t = idx >> 9;
    int s = t & (NS - 1);
    float cv = c[s * 32 + j], sv = sn[s * 32 + j];
    size_t base = (size_t)t * ND + h * 64;
    float q1 = q[base + j], q2 = q[base + 32 + j];
    q[base + j]      = q1 * cv - q2 * sv;
    q[base + 32 + j] = q2 * cv + q1 * sv;
    float k1 = k[base + j], k2 = k[base + 32 + j];
    k[base + j]      = k1 * cv - k2 * sv;
    k[base + 32 + j] = k2 * cv + k1 * sv;
}

// ---------------------------------------------------------------------------
// Tiled fp32 GEMM: C = epilogue(A[M,K] @ W[K,N] + bias[N])
// BM=BN=64, BK=16, 256 threads, 4x4 microtile. M,N multiples of 64; K of 16.
constexpr int BM = 64, BN = 64, BK = 16;

template<bool RELU, bool MOE_ACC>
__global__ __launch_bounds__(256) void gemm_kernel(
    const float* __restrict__ A, const float* __restrict__ W,
    const float* __restrict__ bias, float* __restrict__ C,
    const float* __restrict__ rowscale, int rs_stride,
    int M, int N, int K)
{
    __shared__ alignas(16) float As[BK][BM + 4];
    __shared__ alignas(16) float Ws[BK][BN + 4];
    int tid = threadIdx.x;
    int bm = blockIdx.y * BM;
    int bn = blockIdx.x * BN;
    int tx = tid & 15, ty = tid >> 4;

    int a_m = tid >> 2, a_k = (tid & 3) * 4;
    int w_k = tid >> 4, w_n = (tid & 15) * 4;

    float c[4][4] = {};

    for (int k0 = 0; k0 < K; k0 += BK) {
        float4 av = *(const float4*)(A + (size_t)(bm + a_m) * K + k0 + a_k);
        As[a_k + 0][a_m] = av.x;
        As[a_k + 1][a_m] = av.y;
        As[a_k + 2][a_m] = av.z;
        As[a_k + 3][a_m] = av.w;
        float4 wv = *(const float4*)(W + (size_t)(k0 + w_k) * N + bn + w_n);
        *(float4*)&Ws[w_k][w_n] = wv;
        __syncthreads();
#pragma unroll
        for (int kk = 0; kk < BK; ++kk) {
            float4 a4 = *(const float4*)&As[kk][ty * 4];
            float4 b4 = *(const float4*)&Ws[kk][tx * 4];
            float av2[4] = {a4.x, a4.y, a4.z, a4.w};
            float bv2[4] = {b4.x, b4.y, b4.z, b4.w};
#pragma unroll
            for (int i = 0; i < 4; ++i)
#pragma unroll
                for (int j = 0; j < 4; ++j)
                    c[i][j] = fmaf(av2[i], bv2[j], c[i][j]);
        }
        __syncthreads();
    }

#pragma unroll
    for (int i = 0; i < 4; ++i) {
        int row = bm + ty * 4 + i;
#pragma unroll
        for (int j = 0; j < 4; ++j) {
            int col = bn + tx * 4 + j;
            float val = c[i][j] + bias[col];
            if (RELU) val = fmaxf(val, 0.f);
            size_t idx = (size_t)row * N + col;
            if (MOE_ACC) C[idx] += rowscale[(size_t)row * rs_stride] * val;
            else         C[idx] = val;
        }
    }
}

// ---------------------------------------------------------------------------
// Residual + LayerNorm: out[t] = LN(res[t] + y[t]) * g + b   (res may be null)
__global__ __launch_bounds__(256) void ln_kernel(
    const float* __restrict__ res, const float* __restrict__ y,
    const float* __restrict__ g, const float* __restrict__ b,
    float* __restrict__ outp)
{
    int t = blockIdx.x, tid = threadIdx.x;
    size_t base = (size_t)t * ND;
    float v[4];
    float s = 0.f, s2 = 0.f;
#pragma unroll
    for (int i = 0; i < 4; ++i) {
        int d = tid + 256 * i;
        float val = y[base + d];
        if (res) val += res[base + d];
        v[i] = val;
        s += val;
        s2 += val * val;
    }
    for (int off = 32; off; off >>= 1) {
        s  += __shfl_xor(s, off);
        s2 += __shfl_xor(s2, off);
    }
    __shared__ float rs[4], rs2[4];
    int wave = tid >> 6, lane = tid & 63;
    if (!lane) { rs[wave] = s; rs2[wave] = s2; }
    __syncthreads();
    s = rs[0] + rs[1] + rs[2] + rs[3];
    s2 = rs2[0] + rs2[1] + rs2[2] + rs2[3];
    float mu = s / ND;
    float var = s2 / ND - mu * mu;
    float rstd = rsqrtf(var + 1e-5f);
#pragma unroll
    for (int i = 0; i < 4; ++i) {
        int d = tid + 256 * i;
        outp[base + d] = (v[i] - mu) * rstd * g[d] + b[d];
    }
}

// ---------------------------------------------------------------------------
// Attention: full (non-causal) softmax(QK^T/8)V per (b,h). One wave per q row,
// 4 waves/block sharing K/V LDS tiles of 64 keys.
__global__ __launch_bounds__(256) void attn_kernel(
    const float* __restrict__ q, const float* __restrict__ k,
    const float* __restrict__ v, float* __restrict__ o)
{
    __shared__ alignas(16) float Ks[64][64];
    __shared__ alignas(16) float Vs[64][64];
    int blk = blockIdx.x;              // NB*NH*(NS/4)
    int rt = blk & (NS / 4 - 1);       // 0..255
    int bh = blk >> 8;                 // 0..31
    int b = bh >> 4, h = bh & 15;
    int wave = threadIdx.x >> 6, lane = threadIdx.x & 63;
    int r = rt * 4 + wave;
    size_t qoff = ((size_t)(b * NS + r)) * ND + h * 64;
    float qd = q[qoff + lane];
    float m = -1e30f, l = 0.f, acc = 0.f;

    for (int kt = 0; kt < NS / 64; ++kt) {
        __syncthreads();
#pragma unroll
        for (int p = 0; p < 4; ++p) {
            int row = p * 16 + (threadIdx.x >> 4);
            int f4 = threadIdx.x & 15;
            size_t gg = ((size_t)(b * NS + kt * 64 + row)) * ND + h * 64 + f4 * 4;
            *(float4*)&Ks[row][f4 * 4] = *(const float4*)(k + gg);
            *(float4*)&Vs[row][f4 * 4] = *(const float4*)(v + gg);
        }
        __syncthreads();
        for (int j = 0; j < 64; ++j) {
            float sv = qd * Ks[j][lane];
            for (int off = 32; off; off >>= 1) sv += __shfl_xor(sv, off);
            sv *= 0.125f;
            float mn = fmaxf(m, sv);
            float sc = __expf(m - mn);
            float p = __expf(sv - mn);
            l = l * sc + p;
            acc = acc * sc + p * Vs[j][lane];
            m = mn;
        }
    }
    o[qoff + lane] = acc / l;
}

// ---------------------------------------------------------------------------
// MoE gate: logits = x@gw + gb; top-2 softmax scattered into we[t][8]
__global__ __launch_bounds__(256) void gate_kernel(
    const float* __restrict__ x, const float* __restrict__ gw,
    const float* __restrict__ gb, float* __restrict__ we)
{
    int t = blockIdx.x, tid = threadIdx.x;
    float acc[8] = {};
#pragma unroll
    for (int i = 0; i < 4; ++i) {
        int d = tid * 4 + i;
        float xv = x[(size_t)t * ND + d];
#pragma unroll
        for (int e = 0; e < 8; ++e) acc[e] += xv * gw[d * 8 + e];
    }
    for (int off = 32; off; off >>= 1)
#pragma unroll
        for (int e = 0; e < 8; ++e) acc[e] += __shfl_xor(acc[e], off);
    __shared__ float red[4][8];
    int wave = tid >> 6, lane = tid & 63;
    if (!lane)
#pragma unroll
        for (int e = 0; e < 8; ++e) red[wave][e] = acc[e];
    __syncthreads();
    if (tid == 0) {
        float lg[8];
#pragma unroll
        for (int e = 0; e < 8; ++e)
            lg[e] = red[0][e] + red[1][e] + red[2][e] + red[3][e] + gb[e];
        int i1 = 0;
        for (int e = 1; e < 8; ++e) if (lg[e] > lg[i1]) i1 = e;
        int i2 = -1;
        for (int e = 0; e < 8; ++e) if (e != i1 && (i2 < 0 || lg[e] > lg[i2])) i2 = e;
        float e2 = __expf(lg[i2] - lg[i1]);
        float denom = 1.f + e2;
        float w1 = 1.f / denom, w2 = e2 / denom;
#pragma unroll
        for (int e = 0; e < 8; ++e) we[t * 8 + e] = 0.f;
        we[t * 8 + i1] = w1;
        we[t * 8 + i2] = w2;
    }
}

__global__ void zero_kernel(float* __restrict__ p, int n) {
    int i = blockIdx.x * blockDim.x + threadIdx.x;
    if (i < n) p[i] = 0.f;
}

// ---------------------------------------------------------------------------
extern "C" void kernel_launch(void* const* d_in, const int* in_sizes, int n_in,
                              void* d_out, int out_size, void* d_ws, size_t ws_size,
                              hipStream_t stream) {
    (void)in_sizes; (void)n_in; (void)out_size; (void)ws_size;
    const int*   src  = (const int*)  d_in[0];
    const float* emb  = (const float*)d_in[1];
    const float* qw   = (const float*)d_in[2];
    const float* qb   = (const float*)d_in[3];
    const float* kw   = (const float*)d_in[4];
    const float* kb   = (const float*)d_in[5];
    const float* vw   = (const float*)d_in[6];
    const float* vb   = (const float*)d_in[7];
    const float* ow   = (const float*)d_in[8];
    const float* ob   = (const float*)d_in[9];
    const float* f1w  = (const float*)d_in[10];
    const float* f1b  = (const float*)d_in[11];
    const float* f2w  = (const float*)d_in[12];
    const float* f2b  = (const float*)d_in[13];
    const float* ln1g = (const float*)d_in[14];
    const float* ln1b = (const float*)d_in[15];
    const float* ln2g = (const float*)d_in[16];
    const float* ln2b = (const float*)d_in[17];
    const float* gw   = (const float*)d_in[18];
    const float* gb   = (const float*)d_in[19];
    const float* ew1  = (const float*)d_in[20];
    const float* eb1  = (const float*)d_in[21];
    const float* ew2  = (const float*)d_in[22];
    const float* eb2  = (const float*)d_in[23];
    const float* flng = (const float*)d_in[24];
    const float* flnb = (const float*)d_in[25];
    const float* outw = (const float*)d_in[26];
    const float* outb = (const float*)d_in[27];
    float* out = (float*)d_out;

    float* ws = (float*)d_ws;
    float* xbuf  = ws; ws += (size_t)NT * ND;
    float* qbuf  = ws; ws += (size_t)NT * ND;
    float* kbuf  = ws; ws += (size_t)NT * ND;
    float* vbuf  = ws; ws += (size_t)NT * ND;    // also MoE accumulator
    float* obuf  = ws; ws += (size_t)NT * ND;
    float* tbuf  = ws; ws += (size_t)NT * ND;
    float* hbuf  = ws; ws += (size_t)NT * NDFF;
    float* webuf = ws; ws += (size_t)NT * NE;
    float* cbuf  = ws; ws += (size_t)NS * 32;
    float* snbuf = ws; ws += (size_t)NS * 32;

    yarn_kernel<<<(NS * 32) / 256, 256, 0, stream>>>(cbuf, snbuf);
    embed_kernel<<<(NT * ND) / 256, 256, 0, stream>>>(src, emb, xbuf);

    for (int l = 0; l < NL; ++l) {
        const float* qwl = qw + (size_t)l * ND * ND;
        const float* kwl = kw + (size_t)l * ND * ND;
        const float* vwl = vw + (size_t)l * ND * ND;
        const float* owl = ow + (size_t)l * ND * ND;
        dim3 gdd(ND / BN, NT / BM);
        gemm_kernel<false, false><<<gdd, 256, 0, stream>>>(xbuf, qwl, qb + l * ND, qbuf, nullptr, 0, NT, ND, ND);
        gemm_kernel<false, false><<<gdd, 256, 0, stream>>>(xbuf, kwl, kb + l * ND, kbuf, nullptr, 0, NT, ND, ND);
        gemm_kernel<false, false><<<gdd, 256, 0, stream>>>(xbuf, vwl, vb + l * ND, vbuf, nullptr, 0, NT, ND, ND);
        rope_kernel<<<(NT * NH * 32) / 256, 256, 0, stream>>>(qbuf, kbuf, cbuf, snbuf);
        attn_kernel<<<NB * NH * (NS / 4), 256, 0, stream>>>(qbuf, kbuf, vbuf, obuf);
        gemm_kernel<false, false><<<gdd, 256, 0, stream>>>(obuf, owl, ob + l * ND, tbuf, nullptr, 0, NT, ND, ND);
        ln_kernel<<<NT, 256, 0, stream>>>(xbuf, tbuf, ln1g + l * ND, ln1b + l * ND, xbuf);
        gemm_kernel<true, false><<<dim3(NDFF / BN, NT / BM), 256, 0, stream>>>(
            xbuf, f1w + (size_t)l * ND * NDFF, f1b + l * NDFF, hbuf, nullptr, 0, NT, NDFF, ND);
        gemm_kernel<false, false><<<gdd, 256, 0, stream>>>(
            hbuf, f2w + (size_t)l * NDFF * ND, f2b + l * ND, tbuf, nullptr, 0, NT, ND, NDFF);
        ln_kernel<<<NT, 256, 0, stream>>>(xbuf, tbuf, ln2g + l * ND, ln2b + l * ND, xbuf);
    }

    gate_kernel<<<NT, 256, 0, stream>>>(xbuf, gw, gb, webuf);
    zero_kernel<<<(NT * ND) / 256, 256, 0, stream>>>(vbuf, NT * ND);
    for (int e = 0; e < NE; ++e) {
        gemm_kernel<true, false><<<dim3(NDFF / BN, NT / BM), 256, 0, stream>>>(
            xbuf, ew1 + (size_t)e * ND * NDFF, eb1 + e * NDFF, hbuf, nullptr, 0, NT, NDFF, ND);
        gemm_kernel<false, true><<<dim3(ND / BN, NT / BM), 256, 0, stream>>>(
            hbuf, ew2 + (size_t)e * NDFF * ND, eb2 + e * ND, vbuf, webuf + e, NE, NT, ND, NDFF);
    }
    ln_kernel<<<NT, 256, 0, stream>>>(nullptr, vbuf, flng, flnb, obuf);
    gemm_kernel<false, false><<<dim3(NV / BN, NT / BM), 256, 0, stream>>>(
        obuf, outw, outb, out, nullptr, 0, NT, NV, ND);
}

// Round 5
// 10835.703 us; speedup vs baseline: 1.4735x; 1.4735x over previous
//
#include <hip/hip_runtime.h>
#include <hip/hip_bf16.h>
#include <math.h>

constexpr int NV = 32000, ND = 1024, NH = 16, NHD = 64, NL = 3, NDFF = 4096;
constexpr int NE = 8, NB = 2, NS = 1024, NT = NB * NS;

typedef __attribute__((ext_vector_type(8))) short bf16x8;
typedef __attribute__((ext_vector_type(4))) float f32x4;
typedef __hip_bfloat16 bf16;

__device__ __forceinline__ bf16 f2b(float v) { return __float2bfloat16(v); }

// ---------------------------------------------------------------------------
// YaRN cos/sin table (round-0 proven)
__global__ void yarn_kernel(float* __restrict__ c, float* __restrict__ sn) {
    int idx = blockIdx.x * blockDim.x + threadIdx.x;   // NS*32 threads
    int j = idx & 31;
    int s = idx >> 5;
    double ex = (double)(2 * j) / 64.0;
    double fe = 1.0 / pow(10000.0, ex);
    double fi = fe / 8.0;
    double lin = ((double)j - 8.0) / 13.0;
    double mask = 1.0 - fmin(fmax(lin, 0.0), 1.0);
    double invf = fi * (1.0 - mask) + fe * mask;
    double ms = 0.1 * log(8.0) + 1.0;
    double fr = (double)s * invf;
    c[idx]  = (float)(cos(fr) * ms);
    sn[idx] = (float)(sin(fr) * ms);
}

// ---------------------------------------------------------------------------
__global__ void embed_kernel(const int* __restrict__ src, const float* __restrict__ emb,
                             float* __restrict__ x) {
    int idx = blockIdx.x * blockDim.x + threadIdx.x;   // NT*ND threads
    int t = idx >> 10;
    int d = idx & 1023;
    int s = src[t];
    s = s < 0 ? 0 : (s > NV - 1 ? NV - 1 : s);
    x[idx] = emb[(size_t)s * ND + d] * 32.0f;          // sqrt(1024)=32
}

// ---------------------------------------------------------------------------
// fp32 tiled GEMM (round-0 proven): C = epi(A[M,K] @ W[K,N] + bias[N])
constexpr int BM = 64, BN = 64, BK = 16;

template<bool RELU>
__global__ __launch_bounds__(256) void gemm_kernel(
    const float* __restrict__ A, const float* __restrict__ W,
    const float* __restrict__ bias, float* __restrict__ C,
    int M, int N, int K)
{
    __shared__ alignas(16) float As[BK][BM + 4];
    __shared__ alignas(16) float Ws[BK][BN + 4];
    int tid = threadIdx.x;
    int bm = blockIdx.y * BM;
    int bn = blockIdx.x * BN;
    int tx = tid & 15, ty = tid >> 4;

    int a_m = tid >> 2, a_k = (tid & 3) * 4;
    int w_k = tid >> 4, w_n = (tid & 15) * 4;

    float c[4][4] = {};

    for (int k0 = 0; k0 < K; k0 += BK) {
        float4 av = *(const float4*)(A + (size_t)(bm + a_m) * K + k0 + a_k);
        As[a_k + 0][a_m] = av.x;
        As[a_k + 1][a_m] = av.y;
        As[a_k + 2][a_m] = av.z;
        As[a_k + 3][a_m] = av.w;
        float4 wv = *(const float4*)(W + (size_t)(k0 + w_k) * N + bn + w_n);
        *(float4*)&Ws[w_k][w_n] = wv;
        __syncthreads();
#pragma unroll
        for (int kk = 0; kk < BK; ++kk) {
            float4 a4 = *(const float4*)&As[kk][ty * 4];
            float4 b4 = *(const float4*)&Ws[kk][tx * 4];
            float av2[4] = {a4.x, a4.y, a4.z, a4.w};
            float bv2[4] = {b4.x, b4.y, b4.z, b4.w};
#pragma unroll
            for (int i = 0; i < 4; ++i)
#pragma unroll
                for (int j = 0; j < 4; ++j)
                    c[i][j] = fmaf(av2[i], bv2[j], c[i][j]);
        }
        __syncthreads();
    }

#pragma unroll
    for (int i = 0; i < 4; ++i) {
        int row = bm + ty * 4 + i;
#pragma unroll
        for (int j = 0; j < 4; ++j) {
            int col = bn + tx * 4 + j;
            float val = c[i][j] + bias[col];
            if (RELU) val = fmaxf(val, 0.f);
            C[(size_t)row * N + col] = val;
        }
    }
}

// ---------------------------------------------------------------------------
// Transpose+convert: src fp32 [K][N] -> dst bf16 [N][K]
__global__ __launch_bounds__(256) void wtconv_kernel(
    const float* __restrict__ src, bf16* __restrict__ dst, int K, int N)
{
    __shared__ float tile[32][33];
    int n0 = blockIdx.x * 32, k0 = blockIdx.y * 32;
    int tx = threadIdx.x & 31, ty = threadIdx.x >> 5;   // ty 0..7
#pragma unroll
    for (int i = 0; i < 4; ++i)
        tile[ty + 8 * i][tx] = src[(size_t)(k0 + ty + 8 * i) * N + n0 + tx];
    __syncthreads();
#pragma unroll
    for (int i = 0; i < 4; ++i)
        dst[(size_t)(n0 + ty + 8 * i) * K + k0 + tx] = f2b(tile[tx][ty + 8 * i]);
}

// ---------------------------------------------------------------------------
// bf16 MFMA GEMM: C = epi(A[M,K] @ BT[N,K]^T + bias). 128x128 tile, BK=64.
// EPI: 0=f32 store, 1=bf16 relu store, 3=f32 acc += rowscale*(v+bias)
template<int EPI>
__global__ __launch_bounds__(256) void mm_kernel(
    const bf16* __restrict__ A, const bf16* __restrict__ BT,
    const float* __restrict__ bias, void* __restrict__ Cp,
    const float* __restrict__ rowscale, int M, int N, int K)
{
    __shared__ char smem[32768];                 // As 16KB @0, Bs 16KB @16384
    const int tid = threadIdx.x;
    const int lane = tid & 63, wave = tid >> 6;
    const int wm = wave >> 1, wn = wave & 1;
    const int bm = blockIdx.y * 128, bn = blockIdx.x * 128;
    const int l15 = lane & 15, l4 = lane >> 4;
    const int srow = tid >> 3;                   // 0..31 (row within 32-row pass)
    const int sc = tid & 7;                      // 16B chunk within 128B row

    f32x4 acc[4][4];
#pragma unroll
    for (int i = 0; i < 4; ++i)
#pragma unroll
        for (int j = 0; j < 4; ++j) acc[i][j] = 0.f;

    for (int k0 = 0; k0 < K; k0 += 64) {
#pragma unroll
        for (int p = 0; p < 4; ++p) {
            int row = p * 32 + srow;
            int swc = (sc ^ (row & 7)) << 4;     // swizzled byte offset in row
            bf16x8 av = *(const bf16x8*)(A + (size_t)(bm + row) * K + k0 + sc * 8);
            bf16x8 bv = *(const bf16x8*)(BT + (size_t)(bn + row) * K + k0 + sc * 8);
            *(bf16x8*)(smem + row * 128 + swc) = av;
            *(bf16x8*)(smem + 16384 + row * 128 + swc) = bv;
        }
        __syncthreads();
#pragma unroll
        for (int kk = 0; kk < 2; ++kk) {
            bf16x8 af[4], bfv[4];
            int g = kk * 4 + l4;
#pragma unroll
            for (int mi = 0; mi < 4; ++mi) {
                int row = wm * 64 + mi * 16 + l15;
                af[mi] = *(const bf16x8*)(smem + row * 128 + ((g ^ (row & 7)) << 4));
            }
#pragma unroll
            for (int ni = 0; ni < 4; ++ni) {
                int row = wn * 64 + ni * 16 + l15;
                bfv[ni] = *(const bf16x8*)(smem + 16384 + row * 128 + ((g ^ (row & 7)) << 4));
            }
#pragma unroll
            for (int mi = 0; mi < 4; ++mi)
#pragma unroll
                for (int ni = 0; ni < 4; ++ni)
                    acc[mi][ni] = __builtin_amdgcn_mfma_f32_16x16x32_bf16(
                        af[mi], bfv[ni], acc[mi][ni], 0, 0, 0);
        }
        __syncthreads();
    }
#pragma unroll
    for (int ni = 0; ni < 4; ++ni) {
        int col = bn + wn * 64 + ni * 16 + l15;
        float bv = bias[col];
#pragma unroll
        for (int mi = 0; mi < 4; ++mi) {
#pragma unroll
            for (int rr = 0; rr < 4; ++rr) {
                int row = bm + wm * 64 + mi * 16 + l4 * 4 + rr;
                float v = acc[mi][ni][rr] + bv;
                if (EPI == 1) v = fmaxf(v, 0.f);
                if (EPI == 0)
                    ((float*)Cp)[(size_t)row * N + col] = v;
                else if (EPI == 3)
                    ((float*)Cp)[(size_t)row * N + col] += rowscale[(size_t)row * 8] * v;
                else
                    ((bf16*)Cp)[(size_t)row * N + col] = f2b(v);
            }
        }
    }
}

// ---------------------------------------------------------------------------
// RoPE in-place on fp32 q and k (round-0 proven)
__global__ void rope_kernel(float* __restrict__ q, float* __restrict__ k,
                            const float* __restrict__ c, const float* __restrict__ sn) {
    int idx = blockIdx.x * blockDim.x + threadIdx.x;   // NT*NH*32 threads
    int j = idx & 31;
    int h = (idx >> 5) & 15;
    int t = idx >> 9;
    int s = t & (NS - 1);
    float cv = c[s * 32 + j], sv = sn[s * 32 + j];
    size_t base = (size_t)t * ND + h * 64;
    float q1 = q[base + j], q2 = q[base + 32 + j];
    q[base + j]      = q1 * cv - q2 * sv;
    q[base + 32 + j] = q2 * cv + q1 * sv;
    float k1 = k[base + j], k2 = k[base + 32 + j];
    k[base + j]      = k1 * cv - k2 * sv;
    k[base + 32 + j] = k2 * cv + k1 * sv;
}

// ---------------------------------------------------------------------------
// Attention fp32 (round-0 proven)
__global__ __launch_bounds__(256) void attn_kernel(
    const float* __restrict__ q, const float* __restrict__ k,
    const float* __restrict__ v, float* __restrict__ o)
{
    __shared__ alignas(16) float Ks[64][64];
    __shared__ alignas(16) float Vs[64][64];
    int blk = blockIdx.x;              // NB*NH*(NS/4)
    int rt = blk & (NS / 4 - 1);       // 0..255
    int bh = blk >> 8;                 // 0..31
    int b = bh >> 4, h = bh & 15;
    int wave = threadIdx.x >> 6, lane = threadIdx.x & 63;
    int r = rt * 4 + wave;
    size_t qoff = ((size_t)(b * NS + r)) * ND + h * 64;
    float qd = q[qoff + lane];
    float m = -1e30f, l = 0.f, acc = 0.f;

    for (int kt = 0; kt < NS / 64; ++kt) {
        __syncthreads();
#pragma unroll
        for (int p = 0; p < 4; ++p) {
            int row = p * 16 + (threadIdx.x >> 4);
            int f4 = threadIdx.x & 15;
            size_t gg = ((size_t)(b * NS + kt * 64 + row)) * ND + h * 64 + f4 * 4;
            *(float4*)&Ks[row][f4 * 4] = *(const float4*)(k + gg);
            *(float4*)&Vs[row][f4 * 4] = *(const float4*)(v + gg);
        }
        __syncthreads();
        for (int j = 0; j < 64; ++j) {
            float sv = qd * Ks[j][lane];
            for (int off = 32; off; off >>= 1) sv += __shfl_xor(sv, off);
            sv *= 0.125f;
            float mn = fmaxf(m, sv);
            float sc = __expf(m - mn);
            float p = __expf(sv - mn);
            l = l * sc + p;
            acc = acc * sc + p * Vs[j][lane];
            m = mn;
        }
    }
    o[qoff + lane] = acc / l;
}

// ---------------------------------------------------------------------------
// Residual + LayerNorm fp32 (round-0 proven)
__global__ __launch_bounds__(256) void ln_kernel(
    const float* __restrict__ res, const float* __restrict__ y,
    const float* __restrict__ g, const float* __restrict__ b,
    float* __restrict__ outp)
{
    int t = blockIdx.x, tid = threadIdx.x;
    size_t base = (size_t)t * ND;
    float v[4];
    float s = 0.f, s2 = 0.f;
#pragma unroll
    for (int i = 0; i < 4; ++i) {
        int d = tid + 256 * i;
        float val = y[base + d];
        if (res) val += res[base + d];
        v[i] = val;
        s += val;
        s2 += val * val;
    }
    for (int off = 32; off; off >>= 1) {
        s  += __shfl_xor(s, off);
        s2 += __shfl_xor(s2, off);
    }
    __shared__ float rs[4], rs2[4];
    int wave = tid >> 6, lane = tid & 63;
    if (!lane) { rs[wave] = s; rs2[wave] = s2; }
    __syncthreads();
    s = rs[0] + rs[1] + rs[2] + rs[3];
    s2 = rs2[0] + rs2[1] + rs2[2] + rs2[3];
    float mu = s / ND;
    float var = s2 / ND - mu * mu;
    float rstd = rsqrtf(var + 1e-5f);
#pragma unroll
    for (int i = 0; i < 4; ++i) {
        int d = tid + 256 * i;
        outp[base + d] = (v[i] - mu) * rstd * g[d] + b[d];
    }
}

// ---------------------------------------------------------------------------
// MoE gate (round-0 proven)
__global__ __launch_bounds__(256) void gate_kernel(
    const float* __restrict__ x, const float* __restrict__ gw,
    const float* __restrict__ gb, float* __restrict__ we)
{
    int t = blockIdx.x, tid = threadIdx.x;
    float acc[8] = {};
#pragma unroll
    for (int i = 0; i < 4; ++i) {
        int d = tid * 4 + i;
        float xv = x[(size_t)t * ND + d];
#pragma unroll
        for (int e = 0; e < 8; ++e) acc[e] += xv * gw[d * 8 + e];
    }
    for (int off = 32; off; off >>= 1)
#pragma unroll
        for (int e = 0; e < 8; ++e) acc[e] += __shfl_xor(acc[e], off);
    __shared__ float red[4][8];
    int wave = tid >> 6, lane = tid & 63;
    if (!lane)
#pragma unroll
        for (int e = 0; e < 8; ++e) red[wave][e] = acc[e];
    __syncthreads();
    if (tid == 0) {
        float lg[8];
#pragma unroll
        for (int e = 0; e < 8; ++e)
            lg[e] = red[0][e] + red[1][e] + red[2][e] + red[3][e] + gb[e];
        int i1 = 0;
        for (int e = 1; e < 8; ++e) if (lg[e] > lg[i1]) i1 = e;
        int i2 = -1;
        for (int e = 0; e < 8; ++e) if (e != i1 && (i2 < 0 || lg[e] > lg[i2])) i2 = e;
        float e2 = __expf(lg[i2] - lg[i1]);
        float denom = 1.f + e2;
#pragma unroll
        for (int e = 0; e < 8; ++e) we[t * 8 + e] = 0.f;
        we[t * 8 + i1] = 1.f / denom;
        we[t * 8 + i2] = e2 / denom;
    }
}

__global__ void zero_kernel(float* __restrict__ p, int n) {
    int i = blockIdx.x * blockDim.x + threadIdx.x;
    if (i < n) p[i] = 0.f;
}

__global__ void cast_kernel(const float* __restrict__ src, bf16* __restrict__ dst, int n) {
    int i = blockIdx.x * blockDim.x + threadIdx.x;
    if (i < n) dst[i] = f2b(src[i]);
}

// ---------------------------------------------------------------------------
extern "C" void kernel_launch(void* const* d_in, const int* in_sizes, int n_in,
                              void* d_out, int out_size, void* d_ws, size_t ws_size,
                              hipStream_t stream) {
    (void)in_sizes; (void)n_in; (void)out_size; (void)ws_size;
    const int*   src  = (const int*)  d_in[0];
    const float* emb  = (const float*)d_in[1];
    const float* qw   = (const float*)d_in[2];
    const float* qb   = (const float*)d_in[3];
    const float* kw   = (const float*)d_in[4];
    const float* kb   = (const float*)d_in[5];
    const float* vw   = (const float*)d_in[6];
    const float* vb   = (const float*)d_in[7];
    const float* ow   = (const float*)d_in[8];
    const float* ob   = (const float*)d_in[9];
    const float* f1w  = (const float*)d_in[10];
    const float* f1b  = (const float*)d_in[11];
    const float* f2w  = (const float*)d_in[12];
    const float* f2b_ = (const float*)d_in[13];
    const float* ln1g = (const float*)d_in[14];
    const float* ln1b = (const float*)d_in[15];
    const float* ln2g = (const float*)d_in[16];
    const float* ln2b = (const float*)d_in[17];
    const float* gw   = (const float*)d_in[18];
    const float* gb   = (const float*)d_in[19];
    const float* ew1  = (const float*)d_in[20];
    const float* eb1  = (const float*)d_in[21];
    const float* ew2  = (const float*)d_in[22];
    const float* eb2  = (const float*)d_in[23];
    const float* flng = (const float*)d_in[24];
    const float* flnb = (const float*)d_in[25];
    const float* outw = (const float*)d_in[26];
    const float* outb = (const float*)d_in[27];
    float* out = (float*)d_out;

    char* w = (char*)d_ws;
    size_t off = 0;
    auto alloc = [&](size_t bytes) -> char* {
        size_t cur = (off + 255) & ~(size_t)255;
        off = cur + bytes;
        return w + cur;
    };

    // Pre-gate fp32 buffers (round-0 layout). qbuf..hbuf are contiguous:
    // the 64MB span is reused post-gate for the transposed vocab weight.
    float* xbuf  = (float*)alloc((size_t)NT * ND * 4);
    float* qbuf  = (float*)alloc((size_t)NT * ND * 4);      // ┐
    float* kbuf  = (float*)alloc((size_t)NT * ND * 4);      // │ 64MB contiguous
    float* vbuf  = (float*)alloc((size_t)NT * ND * 4);      // │ (dead post-gate)
    float* tbuf  = (float*)alloc((size_t)NT * ND * 4);      // │
    float* hbuf  = (float*)alloc((size_t)NT * NDFF * 4);    // ┘
    float* obuf  = (float*)alloc((size_t)NT * ND * 4);
    float* macc  = (float*)alloc((size_t)NT * ND * 4);
    bf16*  hb    = (bf16*) alloc((size_t)NT * NDFF * 2);
    bf16*  xb    = (bf16*) alloc((size_t)NT * ND * 2);
    bf16*  lnout = (bf16*) alloc((size_t)NT * ND * 2);
    bf16*  e1t   = (bf16*) alloc((size_t)NDFF * ND * 2);
    bf16*  e2t   = (bf16*) alloc((size_t)ND * NDFF * 2);
    float* webuf = (float*)alloc((size_t)NT * NE * 4);
    float* cbuf  = (float*)alloc((size_t)NS * 32 * 4);
    float* snbuf = (float*)alloc((size_t)NS * 32 * 4);
    bf16*  outwt = (bf16*)qbuf;   // [32000][1024] bf16 = 62.5MB in the dead 64MB span

    yarn_kernel<<<(NS * 32) / 256, 256, 0, stream>>>(cbuf, snbuf);
    embed_kernel<<<(NT * ND) / 256, 256, 0, stream>>>(src, emb, xbuf);

    for (int l = 0; l < NL; ++l) {
        const float* qwl = qw + (size_t)l * ND * ND;
        const float* kwl = kw + (size_t)l * ND * ND;
        const float* vwl = vw + (size_t)l * ND * ND;
        const float* owl = ow + (size_t)l * ND * ND;
        dim3 gdd(ND / BN, NT / BM);
        gemm_kernel<false><<<gdd, 256, 0, stream>>>(xbuf, qwl, qb + l * ND, qbuf, NT, ND, ND);
        gemm_kernel<false><<<gdd, 256, 0, stream>>>(xbuf, kwl, kb + l * ND, kbuf, NT, ND, ND);
        gemm_kernel<false><<<gdd, 256, 0, stream>>>(xbuf, vwl, vb + l * ND, vbuf, NT, ND, ND);
        rope_kernel<<<(NT * NH * 32) / 256, 256, 0, stream>>>(qbuf, kbuf, cbuf, snbuf);
        attn_kernel<<<NB * NH * (NS / 4), 256, 0, stream>>>(qbuf, kbuf, vbuf, obuf);
        gemm_kernel<false><<<gdd, 256, 0, stream>>>(obuf, owl, ob + l * ND, tbuf, NT, ND, ND);
        ln_kernel<<<NT, 256, 0, stream>>>(xbuf, tbuf, ln1g + l * ND, ln1b + l * ND, xbuf);
        gemm_kernel<true><<<dim3(NDFF / BN, NT / BM), 256, 0, stream>>>(
            xbuf, f1w + (size_t)l * ND * NDFF, f1b + l * NDFF, hbuf, NT, NDFF, ND);
        gemm_kernel<false><<<gdd, 256, 0, stream>>>(
            hbuf, f2w + (size_t)l * NDFF * ND, f2b_ + l * ND, tbuf, NT, ND, NDFF);
        ln_kernel<<<NT, 256, 0, stream>>>(xbuf, tbuf, ln2g + l * ND, ln2b + l * ND, xbuf);
    }

    // Gate on exact fp32 x (decisions match reference as in round 0)
    gate_kernel<<<NT, 256, 0, stream>>>(xbuf, gw, gb, webuf);

    // Post-gate: decision-free compute on bf16 MFMA
    cast_kernel<<<(NT * ND) / 256, 256, 0, stream>>>(xbuf, xb, NT * ND);
    zero_kernel<<<(NT * ND) / 256, 256, 0, stream>>>(macc, NT * ND);
    wtconv_kernel<<<dim3(1000, 32), 256, 0, stream>>>(outw, outwt, 1024, 32000);
    for (int e = 0; e < NE; ++e) {
        wtconv_kernel<<<dim3(128, 32), 256, 0, stream>>>(ew1 + (size_t)e * 4194304, e1t, 1024, 4096);
        wtconv_kernel<<<dim3(32, 128), 256, 0, stream>>>(ew2 + (size_t)e * 4194304, e2t, 4096, 1024);
        mm_kernel<1><<<dim3(32, 16), 256, 0, stream>>>(xb, e1t, eb1 + e * 4096, hb, nullptr, NT, 4096, 1024);
        mm_kernel<3><<<dim3(8, 16), 256, 0, stream>>>(hb, e2t, eb2 + e * 1024, macc, webuf + e, NT, 1024, 4096);
    }
    ln_kernel<<<NT, 256, 0, stream>>>(nullptr, macc, flng, flnb, obuf);
    cast_kernel<<<(NT * ND) / 256, 256, 0, stream>>>(obuf, lnout, NT * ND);
    mm_kernel<0><<<dim3(250, 16), 256, 0, stream>>>(lnout, outwt, outb, out, nullptr, NT, NV, 1024);
}

// Round 6
// 6089.311 us; speedup vs baseline: 2.6221x; 1.7795x over previous
//
#include <hip/hip_runtime.h>
#include <hip/hip_bf16.h>
#include <math.h>

constexpr int NV = 32000, ND = 1024, NH = 16, NHD = 64, NL = 3, NDFF = 4096;
constexpr int NE = 8, NB = 2, NS = 1024, NT = NB * NS;

typedef __attribute__((ext_vector_type(8))) short bf16x8;
typedef __attribute__((ext_vector_type(4))) float f32x4;
typedef __hip_bfloat16 bf16;

__device__ __forceinline__ bf16 f2b(float v) { return __float2bfloat16(v); }

// ---------------------------------------------------------------------------
// YaRN cos/sin table (round-0 proven)
__global__ void yarn_kernel(float* __restrict__ c, float* __restrict__ sn) {
    int idx = blockIdx.x * blockDim.x + threadIdx.x;   // NS*32 threads
    int j = idx & 31;
    int s = idx >> 5;
    double ex = (double)(2 * j) / 64.0;
    double fe = 1.0 / pow(10000.0, ex);
    double fi = fe / 8.0;
    double lin = ((double)j - 8.0) / 13.0;
    double mask = 1.0 - fmin(fmax(lin, 0.0), 1.0);
    double invf = fi * (1.0 - mask) + fe * mask;
    double ms = 0.1 * log(8.0) + 1.0;
    double fr = (double)s * invf;
    c[idx]  = (float)(cos(fr) * ms);
    sn[idx] = (float)(sin(fr) * ms);
}

// ---------------------------------------------------------------------------
__global__ void embed_kernel(const int* __restrict__ src, const float* __restrict__ emb,
                             float* __restrict__ x) {
    int idx = blockIdx.x * blockDim.x + threadIdx.x;   // NT*ND threads
    int t = idx >> 10;
    int d = idx & 1023;
    int s = src[t];
    s = s < 0 ? 0 : (s > NV - 1 ? NV - 1 : s);
    x[idx] = emb[(size_t)s * ND + d] * 32.0f;          // sqrt(1024)=32
}

// ---------------------------------------------------------------------------
// fp32 tiled GEMM (round-0 proven): C = epi(A[M,K] @ W[K,N] + bias[N])
constexpr int BM = 64, BN = 64, BK = 16;

template<bool RELU>
__global__ __launch_bounds__(256) void gemm_kernel(
    const float* __restrict__ A, const float* __restrict__ W,
    const float* __restrict__ bias, float* __restrict__ C,
    int M, int N, int K)
{
    __shared__ alignas(16) float As[BK][BM + 4];
    __shared__ alignas(16) float Ws[BK][BN + 4];
    int tid = threadIdx.x;
    int bm = blockIdx.y * BM;
    int bn = blockIdx.x * BN;
    int tx = tid & 15, ty = tid >> 4;

    int a_m = tid >> 2, a_k = (tid & 3) * 4;
    int w_k = tid >> 4, w_n = (tid & 15) * 4;

    float c[4][4] = {};

    for (int k0 = 0; k0 < K; k0 += BK) {
        float4 av = *(const float4*)(A + (size_t)(bm + a_m) * K + k0 + a_k);
        As[a_k + 0][a_m] = av.x;
        As[a_k + 1][a_m] = av.y;
        As[a_k + 2][a_m] = av.z;
        As[a_k + 3][a_m] = av.w;
        float4 wv = *(const float4*)(W + (size_t)(k0 + w_k) * N + bn + w_n);
        *(float4*)&Ws[w_k][w_n] = wv;
        __syncthreads();
#pragma unroll
        for (int kk = 0; kk < BK; ++kk) {
            float4 a4 = *(const float4*)&As[kk][ty * 4];
            float4 b4 = *(const float4*)&Ws[kk][tx * 4];
            float av2[4] = {a4.x, a4.y, a4.z, a4.w};
            float bv2[4] = {b4.x, b4.y, b4.z, b4.w};
#pragma unroll
            for (int i = 0; i < 4; ++i)
#pragma unroll
                for (int j = 0; j < 4; ++j)
                    c[i][j] = fmaf(av2[i], bv2[j], c[i][j]);
        }
        __syncthreads();
    }

#pragma unroll
    for (int i = 0; i < 4; ++i) {
        int row = bm + ty * 4 + i;
#pragma unroll
        for (int j = 0; j < 4; ++j) {
            int col = bn + tx * 4 + j;
            float val = c[i][j] + bias[col];
            if (RELU) val = fmaxf(val, 0.f);
            C[(size_t)row * N + col] = val;
        }
    }
}

// ---------------------------------------------------------------------------
// Transpose+convert: src fp32 [K][N] -> dst bf16 [N][K]
__global__ __launch_bounds__(256) void wtconv_kernel(
    const float* __restrict__ src, bf16* __restrict__ dst, int K, int N)
{
    __shared__ float tile[32][33];
    int n0 = blockIdx.x * 32, k0 = blockIdx.y * 32;
    int tx = threadIdx.x & 31, ty = threadIdx.x >> 5;   // ty 0..7
#pragma unroll
    for (int i = 0; i < 4; ++i)
        tile[ty + 8 * i][tx] = src[(size_t)(k0 + ty + 8 * i) * N + n0 + tx];
    __syncthreads();
#pragma unroll
    for (int i = 0; i < 4; ++i)
        dst[(size_t)(n0 + ty + 8 * i) * K + k0 + tx] = f2b(tile[tx][ty + 8 * i]);
}

// ---------------------------------------------------------------------------
// bf16 MFMA GEMM (proven in round 5): C = epi(A[M,K] @ BT[N,K]^T + bias).
// EPI: 0=f32 store, 1=bf16 relu store, 3=f32 acc += rowscale*(v+bias)
template<int EPI>
__global__ __launch_bounds__(256) void mm_kernel(
    const bf16* __restrict__ A, const bf16* __restrict__ BT,
    const float* __restrict__ bias, void* __restrict__ Cp,
    const float* __restrict__ rowscale, int M, int N, int K)
{
    __shared__ char smem[32768];                 // As 16KB @0, Bs 16KB @16384
    const int tid = threadIdx.x;
    const int lane = tid & 63, wave = tid >> 6;
    const int wm = wave >> 1, wn = wave & 1;
    const int bm = blockIdx.y * 128, bn = blockIdx.x * 128;
    const int l15 = lane & 15, l4 = lane >> 4;
    const int srow = tid >> 3;                   // 0..31 (row within 32-row pass)
    const int sc = tid & 7;                      // 16B chunk within 128B row

    f32x4 acc[4][4];
#pragma unroll
    for (int i = 0; i < 4; ++i)
#pragma unroll
        for (int j = 0; j < 4; ++j) acc[i][j] = 0.f;

    for (int k0 = 0; k0 < K; k0 += 64) {
#pragma unroll
        for (int p = 0; p < 4; ++p) {
            int row = p * 32 + srow;
            int swc = (sc ^ (row & 7)) << 4;     // swizzled byte offset in row
            bf16x8 av = *(const bf16x8*)(A + (size_t)(bm + row) * K + k0 + sc * 8);
            bf16x8 bv = *(const bf16x8*)(BT + (size_t)(bn + row) * K + k0 + sc * 8);
            *(bf16x8*)(smem + row * 128 + swc) = av;
            *(bf16x8*)(smem + 16384 + row * 128 + swc) = bv;
        }
        __syncthreads();
#pragma unroll
        for (int kk = 0; kk < 2; ++kk) {
            bf16x8 af[4], bfv[4];
            int g = kk * 4 + l4;
#pragma unroll
            for (int mi = 0; mi < 4; ++mi) {
                int row = wm * 64 + mi * 16 + l15;
                af[mi] = *(const bf16x8*)(smem + row * 128 + ((g ^ (row & 7)) << 4));
            }
#pragma unroll
            for (int ni = 0; ni < 4; ++ni) {
                int row = wn * 64 + ni * 16 + l15;
                bfv[ni] = *(const bf16x8*)(smem + 16384 + row * 128 + ((g ^ (row & 7)) << 4));
            }
#pragma unroll
            for (int mi = 0; mi < 4; ++mi)
#pragma unroll
                for (int ni = 0; ni < 4; ++ni)
                    acc[mi][ni] = __builtin_amdgcn_mfma_f32_16x16x32_bf16(
                        af[mi], bfv[ni], acc[mi][ni], 0, 0, 0);
        }
        __syncthreads();
    }
#pragma unroll
    for (int ni = 0; ni < 4; ++ni) {
        int col = bn + wn * 64 + ni * 16 + l15;
        float bv = bias[col];
#pragma unroll
        for (int mi = 0; mi < 4; ++mi) {
#pragma unroll
            for (int rr = 0; rr < 4; ++rr) {
                int row = bm + wm * 64 + mi * 16 + l4 * 4 + rr;
                float v = acc[mi][ni][rr] + bv;
                if (EPI == 1) v = fmaxf(v, 0.f);
                if (EPI == 0)
                    ((float*)Cp)[(size_t)row * N + col] = v;
                else if (EPI == 3)
                    ((float*)Cp)[(size_t)row * N + col] += rowscale[(size_t)row * 8] * v;
                else
                    ((bf16*)Cp)[(size_t)row * N + col] = f2b(v);
            }
        }
    }
}

// ---------------------------------------------------------------------------
// RoPE in-place on fp32 q and k (round-0 proven)
__global__ void rope_kernel(float* __restrict__ q, float* __restrict__ k,
                            const float* __restrict__ c, const float* __restrict__ sn) {
    int idx = blockIdx.x * blockDim.x + threadIdx.x;   // NT*NH*32 threads
    int j = idx & 31;
    int h = (idx >> 5) & 15;
    int t = idx >> 9;
    int s = t & (NS - 1);
    float cv = c[s * 32 + j], sv = sn[s * 32 + j];
    size_t base = (size_t)t * ND + h * 64;
    float q1 = q[base + j], q2 = q[base + 32 + j];
    q[base + j]      = q1 * cv - q2 * sv;
    q[base + 32 + j] = q2 * cv + q1 * sv;
    float k1 = k[base + j], k2 = k[base + 32 + j];
    k[base + j]      = k1 * cv - k2 * sv;
    k[base + 32 + j] = k2 * cv + k1 * sv;
}

// ---------------------------------------------------------------------------
// Parallel-key fp32 attention. 4 waves/block = 4 q rows; K/V tiles shared.
// Scores: lane=j (key), vectorized via quad-interleaved K^T tile.
// Softmax: one 64-lane shuffle reduce per tile (not per key).
// PV: lane=d, vectorized via XOR-swizzled quad-interleaved V tile.
__global__ __launch_bounds__(256) void attn_kernel(
    const float* __restrict__ q, const float* __restrict__ k,
    const float* __restrict__ v, float* __restrict__ o)
{
    __shared__ float Kt2[16][64][4];   // [dq][j][dk] = K[j][4*dq+dk]
    __shared__ float Vt2[16][64][4];   // [jq][d ^ (jq&7)][jk] = V[4*jq+jk][d]
    __shared__ float qs[4][64];
    __shared__ float ps[4][64];

    int blk = blockIdx.x;              // NB*NH*(NS/4)
    int rt = blk & (NS / 4 - 1);       // 0..255
    int bh = blk >> 8;                 // 0..31
    int b = bh >> 4, h = bh & 15;
    int wave = threadIdx.x >> 6, lane = threadIdx.x & 63;
    int r = rt * 4 + wave;
    size_t qoff = ((size_t)(b * NS + r)) * ND + h * 64;
    qs[wave][lane] = q[qoff + lane] * 0.125f;   // fold 1/sqrt(64) (exact pow2)

    float m = -1e30f, l = 0.f, oacc = 0.f;

    for (int kt = 0; kt < NS / 64; ++kt) {
        __syncthreads();
#pragma unroll
        for (int p = 0; p < 4; ++p) {
            int row = p * 16 + (threadIdx.x >> 4);   // key row 0..63
            int f4 = threadIdx.x & 15;               // 16B chunk over d
            size_t gg = ((size_t)(b * NS + kt * 64 + row)) * ND + h * 64 + f4 * 4;
            float4 kv = *(const float4*)(k + gg);
            float4 vv = *(const float4*)(v + gg);
            *(float4*)&Kt2[f4][row][0] = kv;         // b128, distinct 16B slots
            int jq = row >> 2, jk = row & 3, sw = jq & 7;
            Vt2[jq][(f4 * 4 + 0) ^ sw][jk] = vv.x;   // 2-way max (free)
            Vt2[jq][(f4 * 4 + 1) ^ sw][jk] = vv.y;
            Vt2[jq][(f4 * 4 + 2) ^ sw][jk] = vv.z;
            Vt2[jq][(f4 * 4 + 3) ^ sw][jk] = vv.w;
        }
        __syncthreads();

        // ---- scores: lane = key j
        float sa0 = 0.f, sa1 = 0.f, sa2 = 0.f, sa3 = 0.f;
#pragma unroll
        for (int dq = 0; dq < 16; dq += 4) {
            float4 q0 = *(const float4*)&qs[wave][(dq + 0) * 4];
            float4 k0v = *(const float4*)&Kt2[dq + 0][lane][0];
            sa0 = fmaf(q0.x, k0v.x, fmaf(q0.y, k0v.y, fmaf(q0.z, k0v.z, fmaf(q0.w, k0v.w, sa0))));
            float4 q1 = *(const float4*)&qs[wave][(dq + 1) * 4];
            float4 k1v = *(const float4*)&Kt2[dq + 1][lane][0];
            sa1 = fmaf(q1.x, k1v.x, fmaf(q1.y, k1v.y, fmaf(q1.z, k1v.z, fmaf(q1.w, k1v.w, sa1))));
            float4 q2 = *(const float4*)&qs[wave][(dq + 2) * 4];
            float4 k2v = *(const float4*)&Kt2[dq + 2][lane][0];
            sa2 = fmaf(q2.x, k2v.x, fmaf(q2.y, k2v.y, fmaf(q2.z, k2v.z, fmaf(q2.w, k2v.w, sa2))));
            float4 q3 = *(const float4*)&qs[wave][(dq + 3) * 4];
            float4 k3v = *(const float4*)&Kt2[dq + 3][lane][0];
            sa3 = fmaf(q3.x, k3v.x, fmaf(q3.y, k3v.y, fmaf(q3.z, k3v.z, fmaf(q3.w, k3v.w, sa3))));
        }
        float s = (sa0 + sa1) + (sa2 + sa3);

        // ---- online softmax (one reduce per tile)
        float mt = s;
#pragma unroll
        for (int off2 = 32; off2; off2 >>= 1) mt = fmaxf(mt, __shfl_xor(mt, off2));
        float mn = fmaxf(m, mt);
        float pj = __expf(s - mn);
        float ts = pj;
#pragma unroll
        for (int off2 = 32; off2; off2 >>= 1) ts += __shfl_xor(ts, off2);
        float scale = __expf(m - mn);
        l = l * scale + ts;
        m = mn;
        ps[wave][lane] = pj;

        // ---- PV: lane = output dim d
        float pv0 = 0.f, pv1 = 0.f, pv2 = 0.f, pv3 = 0.f;
#pragma unroll
        for (int jq = 0; jq < 16; jq += 4) {
            float4 p0 = *(const float4*)&ps[wave][(jq + 0) * 4];
            float4 v0 = *(const float4*)&Vt2[jq + 0][lane ^ ((jq + 0) & 7)][0];
            pv0 = fmaf(p0.x, v0.x, fmaf(p0.y, v0.y, fmaf(p0.z, v0.z, fmaf(p0.w, v0.w, pv0))));
            float4 p1 = *(const float4*)&ps[wave][(jq + 1) * 4];
            float4 v1 = *(const float4*)&Vt2[jq + 1][lane ^ ((jq + 1) & 7)][0];
            pv1 = fmaf(p1.x, v1.x, fmaf(p1.y, v1.y, fmaf(p1.z, v1.z, fmaf(p1.w, v1.w, pv1))));
            float4 p2 = *(const float4*)&ps[wave][(jq + 2) * 4];
            float4 v2 = *(const float4*)&Vt2[jq + 2][lane ^ ((jq + 2) & 7)][0];
            pv2 = fmaf(p2.x, v2.x, fmaf(p2.y, v2.y, fmaf(p2.z, v2.z, fmaf(p2.w, v2.w, pv2))));
            float4 p3 = *(const float4*)&ps[wave][(jq + 3) * 4];
            float4 v3 = *(const float4*)&Vt2[jq + 3][lane ^ ((jq + 3) & 7)][0];
            pv3 = fmaf(p3.x, v3.x, fmaf(p3.y, v3.y, fmaf(p3.z, v3.z, fmaf(p3.w, v3.w, pv3))));
        }
        oacc = oacc * scale + ((pv0 + pv1) + (pv2 + pv3));
    }
    o[qoff + lane] = oacc / l;
}

// ---------------------------------------------------------------------------
// Residual + LayerNorm fp32 (round-0 proven)
__global__ __launch_bounds__(256) void ln_kernel(
    const float* __restrict__ res, const float* __restrict__ y,
    const float* __restrict__ g, const float* __restrict__ b,
    float* __restrict__ outp)
{
    int t = blockIdx.x, tid = threadIdx.x;
    size_t base = (size_t)t * ND;
    float v[4];
    float s = 0.f, s2 = 0.f;
#pragma unroll
    for (int i = 0; i < 4; ++i) {
        int d = tid + 256 * i;
        float val = y[base + d];
        if (res) val += res[base + d];
        v[i] = val;
        s += val;
        s2 += val * val;
    }
    for (int off = 32; off; off >>= 1) {
        s  += __shfl_xor(s, off);
        s2 += __shfl_xor(s2, off);
    }
    __shared__ float rs[4], rs2[4];
    int wave = tid >> 6, lane = tid & 63;
    if (!lane) { rs[wave] = s; rs2[wave] = s2; }
    __syncthreads();
    s = rs[0] + rs[1] + rs[2] + rs[3];
    s2 = rs2[0] + rs2[1] + rs2[2] + rs2[3];
    float mu = s / ND;
    float var = s2 / ND - mu * mu;
    float rstd = rsqrtf(var + 1e-5f);
#pragma unroll
    for (int i = 0; i < 4; ++i) {
        int d = tid + 256 * i;
        outp[base + d] = (v[i] - mu) * rstd * g[d] + b[d];
    }
}

// ---------------------------------------------------------------------------
// MoE gate (round-0 proven)
__global__ __launch_bounds__(256) void gate_kernel(
    const float* __restrict__ x, const float* __restrict__ gw,
    const float* __restrict__ gb, float* __restrict__ we)
{
    int t = blockIdx.x, tid = threadIdx.x;
    float acc[8] = {};
#pragma unroll
    for (int i = 0; i < 4; ++i) {
        int d = tid * 4 + i;
        float xv = x[(size_t)t * ND + d];
#pragma unroll
        for (int e = 0; e < 8; ++e) acc[e] += xv * gw[d * 8 + e];
    }
    for (int off = 32; off; off >>= 1)
#pragma unroll
        for (int e = 0; e < 8; ++e) acc[e] += __shfl_xor(acc[e], off);
    __shared__ float red[4][8];
    int wave = tid >> 6, lane = tid & 63;
    if (!lane)
#pragma unroll
        for (int e = 0; e < 8; ++e) red[wave][e] = acc[e];
    __syncthreads();
    if (tid == 0) {
        float lg[8];
#pragma unroll
        for (int e = 0; e < 8; ++e)
            lg[e] = red[0][e] + red[1][e] + red[2][e] + red[3][e] + gb[e];
        int i1 = 0;
        for (int e = 1; e < 8; ++e) if (lg[e] > lg[i1]) i1 = e;
        int i2 = -1;
        for (int e = 0; e < 8; ++e) if (e != i1 && (i2 < 0 || lg[e] > lg[i2])) i2 = e;
        float e2 = __expf(lg[i2] - lg[i1]);
        float denom = 1.f + e2;
#pragma unroll
        for (int e = 0; e < 8; ++e) we[t * 8 + e] = 0.f;
        we[t * 8 + i1] = 1.f / denom;
        we[t * 8 + i2] = e2 / denom;
    }
}

__global__ void zero_kernel(float* __restrict__ p, int n) {
    int i = blockIdx.x * blockDim.x + threadIdx.x;
    if (i < n) p[i] = 0.f;
}

__global__ void cast_kernel(const float* __restrict__ src, bf16* __restrict__ dst, int n) {
    int i = blockIdx.x * blockDim.x + threadIdx.x;
    if (i < n) dst[i] = f2b(src[i]);
}

// ---------------------------------------------------------------------------
extern "C" void kernel_launch(void* const* d_in, const int* in_sizes, int n_in,
                              void* d_out, int out_size, void* d_ws, size_t ws_size,
                              hipStream_t stream) {
    (void)in_sizes; (void)n_in; (void)out_size; (void)ws_size;
    const int*   src  = (const int*)  d_in[0];
    const float* emb  = (const float*)d_in[1];
    const float* qw   = (const float*)d_in[2];
    const float* qb   = (const float*)d_in[3];
    const float* kw   = (const float*)d_in[4];
    const float* kb   = (const float*)d_in[5];
    const float* vw   = (const float*)d_in[6];
    const float* vb   = (const float*)d_in[7];
    const float* ow   = (const float*)d_in[8];
    const float* ob   = (const float*)d_in[9];
    const float* f1w  = (const float*)d_in[10];
    const float* f1b  = (const float*)d_in[11];
    const float* f2w  = (const float*)d_in[12];
    const float* f2b_ = (const float*)d_in[13];
    const float* ln1g = (const float*)d_in[14];
    const float* ln1b = (const float*)d_in[15];
    const float* ln2g = (const float*)d_in[16];
    const float* ln2b = (const float*)d_in[17];
    const float* gw   = (const float*)d_in[18];
    const float* gb   = (const float*)d_in[19];
    const float* ew1  = (const float*)d_in[20];
    const float* eb1  = (const float*)d_in[21];
    const float* ew2  = (const float*)d_in[22];
    const float* eb2  = (const float*)d_in[23];
    const float* flng = (const float*)d_in[24];
    const float* flnb = (const float*)d_in[25];
    const float* outw = (const float*)d_in[26];
    const float* outb = (const float*)d_in[27];
    float* out = (float*)d_out;

    char* w = (char*)d_ws;
    size_t off = 0;
    auto alloc = [&](size_t bytes) -> char* {
        size_t cur = (off + 255) & ~(size_t)255;
        off = cur + bytes;
        return w + cur;
    };

    // Pre-gate fp32 buffers (round-0 layout). qbuf..hbuf are contiguous:
    // the 64MB span is reused post-gate for the transposed vocab weight.
    float* xbuf  = (float*)alloc((size_t)NT * ND * 4);
    float* qbuf  = (float*)alloc((size_t)NT * ND * 4);      // ┐
    float* kbuf  = (float*)alloc((size_t)NT * ND * 4);      // │ 64MB contiguous
    float* vbuf  = (float*)alloc((size_t)NT * ND * 4);      // │ (dead post-gate)
    float* tbuf  = (float*)alloc((size_t)NT * ND * 4);      // │
    float* hbuf  = (float*)alloc((size_t)NT * NDFF * 4);    // ┘
    float* obuf  = (float*)alloc((size_t)NT * ND * 4);
    float* macc  = (float*)alloc((size_t)NT * ND * 4);
    bf16*  hb    = (bf16*) alloc((size_t)NT * NDFF * 2);
    bf16*  xb    = (bf16*) alloc((size_t)NT * ND * 2);
    bf16*  lnout = (bf16*) alloc((size_t)NT * ND * 2);
    bf16*  e1t   = (bf16*) alloc((size_t)NDFF * ND * 2);
    bf16*  e2t   = (bf16*) alloc((size_t)ND * NDFF * 2);
    float* webuf = (float*)alloc((size_t)NT * NE * 4);
    float* cbuf  = (float*)alloc((size_t)NS * 32 * 4);
    float* snbuf = (float*)alloc((size_t)NS * 32 * 4);
    bf16*  outwt = (bf16*)qbuf;   // [32000][1024] bf16 = 62.5MB in the dead 64MB span

    yarn_kernel<<<(NS * 32) / 256, 256, 0, stream>>>(cbuf, snbuf);
    embed_kernel<<<(NT * ND) / 256, 256, 0, stream>>>(src, emb, xbuf);

    for (int l = 0; l < NL; ++l) {
        const float* qwl = qw + (size_t)l * ND * ND;
        const float* kwl = kw + (size_t)l * ND * ND;
        const float* vwl = vw + (size_t)l * ND * ND;
        const float* owl = ow + (size_t)l * ND * ND;
        dim3 gdd(ND / BN, NT / BM);
        gemm_kernel<false><<<gdd, 256, 0, stream>>>(xbuf, qwl, qb + l * ND, qbuf, NT, ND, ND);
        gemm_kernel<false><<<gdd, 256, 0, stream>>>(xbuf, kwl, kb + l * ND, kbuf, NT, ND, ND);
        gemm_kernel<false><<<gdd, 256, 0, stream>>>(xbuf, vwl, vb + l * ND, vbuf, NT, ND, ND);
        rope_kernel<<<(NT * NH * 32) / 256, 256, 0, stream>>>(qbuf, kbuf, cbuf, snbuf);
        attn_kernel<<<NB * NH * (NS / 4), 256, 0, stream>>>(qbuf, kbuf, vbuf, obuf);
        gemm_kernel<false><<<gdd, 256, 0, stream>>>(obuf, owl, ob + l * ND, tbuf, NT, ND, ND);
        ln_kernel<<<NT, 256, 0, stream>>>(xbuf, tbuf, ln1g + l * ND, ln1b + l * ND, xbuf);
        gemm_kernel<true><<<dim3(NDFF / BN, NT / BM), 256, 0, stream>>>(
            xbuf, f1w + (size_t)l * ND * NDFF, f1b + l * NDFF, hbuf, NT, NDFF, ND);
        gemm_kernel<false><<<gdd, 256, 0, stream>>>(
            hbuf, f2w + (size_t)l * NDFF * ND, f2b_ + l * ND, tbuf, NT, ND, NDFF);
        ln_kernel<<<NT, 256, 0, stream>>>(xbuf, tbuf, ln2g + l * ND, ln2b + l * ND, xbuf);
    }

    // Gate on exact fp32 x (decisions match reference)
    gate_kernel<<<NT, 256, 0, stream>>>(xbuf, gw, gb, webuf);

    // Post-gate: decision-free compute on bf16 MFMA
    cast_kernel<<<(NT * ND) / 256, 256, 0, stream>>>(xbuf, xb, NT * ND);
    zero_kernel<<<(NT * ND) / 256, 256, 0, stream>>>(macc, NT * ND);
    wtconv_kernel<<<dim3(1000, 32), 256, 0, stream>>>(outw, outwt, 1024, 32000);
    for (int e = 0; e < NE; ++e) {
        wtconv_kernel<<<dim3(128, 32), 256, 0, stream>>>(ew1 + (size_t)e * 4194304, e1t, 1024, 4096);
        wtconv_kernel<<<dim3(32, 128), 256, 0, stream>>>(ew2 + (size_t)e * 4194304, e2t, 4096, 1024);
        mm_kernel<1><<<dim3(32, 16), 256, 0, stream>>>(xb, e1t, eb1 + e * 4096, hb, nullptr, NT, 4096, 1024);
        mm_kernel<3><<<dim3(8, 16), 256, 0, stream>>>(hb, e2t, eb2 + e * 1024, macc, webuf + e, NT, 1024, 4096);
    }
    ln_kernel<<<NT, 256, 0, stream>>>(nullptr, macc, flng, flnb, obuf);
    cast_kernel<<<(NT * ND) / 256, 256, 0, stream>>>(obuf, lnout, NT * ND);
    mm_kernel<0><<<dim3(250, 16), 256, 0, stream>>>(lnout, outwt, outb, out, nullptr, NT, NV, 1024);
}

// Round 7
// 5334.702 us; speedup vs baseline: 2.9930x; 1.1415x over previous
//
#include <hip/hip_runtime.h>
#include <hip/hip_bf16.h>
#include <math.h>

constexpr int NV = 32000, ND = 1024, NH = 16, NHD = 64, NL = 3, NDFF = 4096;
constexpr int NE = 8, NB = 2, NS = 1024, NT = NB * NS;

typedef __attribute__((ext_vector_type(8))) short bf16x8;
typedef __attribute__((ext_vector_type(4))) float f32x4;
typedef __hip_bfloat16 bf16;

__device__ __forceinline__ bf16 f2b(float v) { return __float2bfloat16(v); }

// ---------------------------------------------------------------------------
// YaRN cos/sin table (round-0 proven)
__global__ void yarn_kernel(float* __restrict__ c, float* __restrict__ sn) {
    int idx = blockIdx.x * blockDim.x + threadIdx.x;   // NS*32 threads
    int j = idx & 31;
    int s = idx >> 5;
    double ex = (double)(2 * j) / 64.0;
    double fe = 1.0 / pow(10000.0, ex);
    double fi = fe / 8.0;
    double lin = ((double)j - 8.0) / 13.0;
    double mask = 1.0 - fmin(fmax(lin, 0.0), 1.0);
    double invf = fi * (1.0 - mask) + fe * mask;
    double ms = 0.1 * log(8.0) + 1.0;
    double fr = (double)s * invf;
    c[idx]  = (float)(cos(fr) * ms);
    sn[idx] = (float)(sin(fr) * ms);
}

// ---------------------------------------------------------------------------
__global__ void embed_kernel(const int* __restrict__ src, const float* __restrict__ emb,
                             float* __restrict__ x) {
    int idx = blockIdx.x * blockDim.x + threadIdx.x;   // NT*ND threads
    int t = idx >> 10;
    int d = idx & 1023;
    int s = src[t];
    s = s < 0 ? 0 : (s > NV - 1 ? NV - 1 : s);
    x[idx] = emb[(size_t)s * ND + d] * 32.0f;          // sqrt(1024)=32
}

// ---------------------------------------------------------------------------
// fp32 tiled GEMM (round-0 proven): C = epi(A[M,K] @ W[K,N] + bias[N])
constexpr int BM = 64, BN = 64, BK = 16;

template<bool RELU>
__global__ __launch_bounds__(256) void gemm_kernel(
    const float* __restrict__ A, const float* __restrict__ W,
    const float* __restrict__ bias, float* __restrict__ C,
    int M, int N, int K)
{
    __shared__ alignas(16) float As[BK][BM + 4];
    __shared__ alignas(16) float Ws[BK][BN + 4];
    int tid = threadIdx.x;
    int bm = blockIdx.y * BM;
    int bn = blockIdx.x * BN;
    int tx = tid & 15, ty = tid >> 4;

    int a_m = tid >> 2, a_k = (tid & 3) * 4;
    int w_k = tid >> 4, w_n = (tid & 15) * 4;

    float c[4][4] = {};

    for (int k0 = 0; k0 < K; k0 += BK) {
        float4 av = *(const float4*)(A + (size_t)(bm + a_m) * K + k0 + a_k);
        As[a_k + 0][a_m] = av.x;
        As[a_k + 1][a_m] = av.y;
        As[a_k + 2][a_m] = av.z;
        As[a_k + 3][a_m] = av.w;
        float4 wv = *(const float4*)(W + (size_t)(k0 + w_k) * N + bn + w_n);
        *(float4*)&Ws[w_k][w_n] = wv;
        __syncthreads();
#pragma unroll
        for (int kk = 0; kk < BK; ++kk) {
            float4 a4 = *(const float4*)&As[kk][ty * 4];
            float4 b4 = *(const float4*)&Ws[kk][tx * 4];
            float av2[4] = {a4.x, a4.y, a4.z, a4.w};
            float bv2[4] = {b4.x, b4.y, b4.z, b4.w};
#pragma unroll
            for (int i = 0; i < 4; ++i)
#pragma unroll
                for (int j = 0; j < 4; ++j)
                    c[i][j] = fmaf(av2[i], bv2[j], c[i][j]);
        }
        __syncthreads();
    }

#pragma unroll
    for (int i = 0; i < 4; ++i) {
        int row = bm + ty * 4 + i;
#pragma unroll
        for (int j = 0; j < 4; ++j) {
            int col = bn + tx * 4 + j;
            float val = c[i][j] + bias[col];
            if (RELU) val = fmaxf(val, 0.f);
            C[(size_t)row * N + col] = val;
        }
    }
}

// ---------------------------------------------------------------------------
// Transpose+convert: src fp32 [K][N] -> dst bf16 [N][K]
__global__ __launch_bounds__(256) void wtconv_kernel(
    const float* __restrict__ src, bf16* __restrict__ dst, int K, int N)
{
    __shared__ float tile[32][33];
    int n0 = blockIdx.x * 32, k0 = blockIdx.y * 32;
    int tx = threadIdx.x & 31, ty = threadIdx.x >> 5;   // ty 0..7
#pragma unroll
    for (int i = 0; i < 4; ++i)
        tile[ty + 8 * i][tx] = src[(size_t)(k0 + ty + 8 * i) * N + n0 + tx];
    __syncthreads();
#pragma unroll
    for (int i = 0; i < 4; ++i)
        dst[(size_t)(n0 + ty + 8 * i) * K + k0 + tx] = f2b(tile[tx][ty + 8 * i]);
}

// ---------------------------------------------------------------------------
// bf16 MFMA GEMM (proven in round 5): C = epi(A[M,K] @ BT[N,K]^T + bias).
// EPI: 0=f32 store, 1=bf16 relu store, 3=f32 acc += rowscale*(v+bias)
template<int EPI>
__global__ __launch_bounds__(256) void mm_kernel(
    const bf16* __restrict__ A, const bf16* __restrict__ BT,
    const float* __restrict__ bias, void* __restrict__ Cp,
    const float* __restrict__ rowscale, int M, int N, int K)
{
    __shared__ char smem[32768];                 // As 16KB @0, Bs 16KB @16384
    const int tid = threadIdx.x;
    const int lane = tid & 63, wave = tid >> 6;
    const int wm = wave >> 1, wn = wave & 1;
    const int bm = blockIdx.y * 128, bn = blockIdx.x * 128;
    const int l15 = lane & 15, l4 = lane >> 4;
    const int srow = tid >> 3;                   // 0..31 (row within 32-row pass)
    const int sc = tid & 7;                      // 16B chunk within 128B row

    f32x4 acc[4][4];
#pragma unroll
    for (int i = 0; i < 4; ++i)
#pragma unroll
        for (int j = 0; j < 4; ++j) acc[i][j] = 0.f;

    for (int k0 = 0; k0 < K; k0 += 64) {
#pragma unroll
        for (int p = 0; p < 4; ++p) {
            int row = p * 32 + srow;
            int swc = (sc ^ (row & 7)) << 4;     // swizzled byte offset in row
            bf16x8 av = *(const bf16x8*)(A + (size_t)(bm + row) * K + k0 + sc * 8);
            bf16x8 bv = *(const bf16x8*)(BT + (size_t)(bn + row) * K + k0 + sc * 8);
            *(bf16x8*)(smem + row * 128 + swc) = av;
            *(bf16x8*)(smem + 16384 + row * 128 + swc) = bv;
        }
        __syncthreads();
#pragma unroll
        for (int kk = 0; kk < 2; ++kk) {
            bf16x8 af[4], bfv[4];
            int g = kk * 4 + l4;
#pragma unroll
            for (int mi = 0; mi < 4; ++mi) {
                int row = wm * 64 + mi * 16 + l15;
                af[mi] = *(const bf16x8*)(smem + row * 128 + ((g ^ (row & 7)) << 4));
            }
#pragma unroll
            for (int ni = 0; ni < 4; ++ni) {
                int row = wn * 64 + ni * 16 + l15;
                bfv[ni] = *(const bf16x8*)(smem + 16384 + row * 128 + ((g ^ (row & 7)) << 4));
            }
#pragma unroll
            for (int mi = 0; mi < 4; ++mi)
#pragma unroll
                for (int ni = 0; ni < 4; ++ni)
                    acc[mi][ni] = __builtin_amdgcn_mfma_f32_16x16x32_bf16(
                        af[mi], bfv[ni], acc[mi][ni], 0, 0, 0);
        }
        __syncthreads();
    }
#pragma unroll
    for (int ni = 0; ni < 4; ++ni) {
        int col = bn + wn * 64 + ni * 16 + l15;
        float bv = bias[col];
#pragma unroll
        for (int mi = 0; mi < 4; ++mi) {
#pragma unroll
            for (int rr = 0; rr < 4; ++rr) {
                int row = bm + wm * 64 + mi * 16 + l4 * 4 + rr;
                float v = acc[mi][ni][rr] + bv;
                if (EPI == 1) v = fmaxf(v, 0.f);
                if (EPI == 0)
                    ((float*)Cp)[(size_t)row * N + col] = v;
                else if (EPI == 3)
                    ((float*)Cp)[(size_t)row * N + col] += rowscale[(size_t)row * 8] * v;
                else
                    ((bf16*)Cp)[(size_t)row * N + col] = f2b(v);
            }
        }
    }
}

// ---------------------------------------------------------------------------
// RoPE in-place on fp32 q and k (round-0 proven)
__global__ void rope_kernel(float* __restrict__ q, float* __restrict__ k,
                            const float* __restrict__ c, const float* __restrict__ sn) {
    int idx = blockIdx.x * blockDim.x + threadIdx.x;   // NT*NH*32 threads
    int j = idx & 31;
    int h = (idx >> 5) & 15;
    int t = idx >> 9;
    int s = t & (NS - 1);
    float cv = c[s * 32 + j], sv = sn[s * 32 + j];
    size_t base = (size_t)t * ND + h * 64;
    float q1 = q[base + j], q2 = q[base + 32 + j];
    q[base + j]      = q1 * cv - q2 * sv;
    q[base + 32 + j] = q2 * cv + q1 * sv;
    float k1 = k[base + j], k2 = k[base + 32 + j];
    k[base + j]      = k1 * cv - k2 * sv;
    k[base + 32 + j] = k2 * cv + k1 * sv;
}

// ---------------------------------------------------------------------------
// Parallel-key fp32 attention, conflict-free LDS layouts.
// K and V both staged as 16B-chunk transposed tiles with padded chunk stride:
//   Kt[f4][j][c] = K[j][f4*4+c], row stride 65*16B=1040B (4 banks mod 32).
// Writes: bank = 4*(f4+row) mod 32 -> 8 accesses/bank (balanced, ~free).
// Scores read: lane-contiguous b128 (conflict-free).
// PV read: Vt[d>>2][j][d&3], lane=d -> banks 0..31 covered twice (free).
__global__ __launch_bounds__(256) void attn_kernel(
    const float* __restrict__ q, const float* __restrict__ k,
    const float* __restrict__ v, float* __restrict__ o)
{
    __shared__ float Kt[16][65][4];
    __shared__ float Vt[16][65][4];
    __shared__ float qs[4][64];
    __shared__ float ps[4][64];

    int blk = blockIdx.x;              // NB*NH*(NS/4)
    int rt = blk & (NS / 4 - 1);       // 0..255
    int bh = blk >> 8;                 // 0..31
    int b = bh >> 4, h = bh & 15;
    int wave = threadIdx.x >> 6, lane = threadIdx.x & 63;
    int r = rt * 4 + wave;
    size_t qoff = ((size_t)(b * NS + r)) * ND + h * 64;
    qs[wave][lane] = q[qoff + lane] * 0.125f;   // fold 1/sqrt(64) (exact pow2)

    const int dq = lane >> 2, dk = lane & 3;    // PV addressing (lane = d)

    float m = -1e30f, l = 0.f, oacc = 0.f;

    for (int kt = 0; kt < NS / 64; ++kt) {
        __syncthreads();
#pragma unroll
        for (int p = 0; p < 4; ++p) {
            int row = p * 16 + (threadIdx.x >> 4);   // key row 0..63
            int f4 = threadIdx.x & 15;               // 16B chunk over d
            size_t gg = ((size_t)(b * NS + kt * 64 + row)) * ND + h * 64 + f4 * 4;
            float4 kv = *(const float4*)(k + gg);
            float4 vv = *(const float4*)(v + gg);
            *(float4*)&Kt[f4][row][0] = kv;
            *(float4*)&Vt[f4][row][0] = vv;
        }
        __syncthreads();

        // ---- scores: lane = key j
        float sa0 = 0.f, sa1 = 0.f, sa2 = 0.f, sa3 = 0.f;
#pragma unroll
        for (int dd = 0; dd < 16; dd += 4) {
            float4 q0 = *(const float4*)&qs[wave][(dd + 0) * 4];
            float4 k0v = *(const float4*)&Kt[dd + 0][lane][0];
            sa0 = fmaf(q0.x, k0v.x, fmaf(q0.y, k0v.y, fmaf(q0.z, k0v.z, fmaf(q0.w, k0v.w, sa0))));
            float4 q1 = *(const float4*)&qs[wave][(dd + 1) * 4];
            float4 k1v = *(const float4*)&Kt[dd + 1][lane][0];
            sa1 = fmaf(q1.x, k1v.x, fmaf(q1.y, k1v.y, fmaf(q1.z, k1v.z, fmaf(q1.w, k1v.w, sa1))));
            float4 q2 = *(const float4*)&qs[wave][(dd + 2) * 4];
            float4 k2v = *(const float4*)&Kt[dd + 2][lane][0];
            sa2 = fmaf(q2.x, k2v.x, fmaf(q2.y, k2v.y, fmaf(q2.z, k2v.z, fmaf(q2.w, k2v.w, sa2))));
            float4 q3 = *(const float4*)&qs[wave][(dd + 3) * 4];
            float4 k3v = *(const float4*)&Kt[dd + 3][lane][0];
            sa3 = fmaf(q3.x, k3v.x, fmaf(q3.y, k3v.y, fmaf(q3.z, k3v.z, fmaf(q3.w, k3v.w, sa3))));
        }
        float s = (sa0 + sa1) + (sa2 + sa3);

        // ---- online softmax (one reduce per tile)
        float mt = s;
#pragma unroll
        for (int off2 = 32; off2; off2 >>= 1) mt = fmaxf(mt, __shfl_xor(mt, off2));
        float mn = fmaxf(m, mt);
        float pj = __expf(s - mn);
        float ts = pj;
#pragma unroll
        for (int off2 = 32; off2; off2 >>= 1) ts += __shfl_xor(ts, off2);
        float scale = __expf(m - mn);
        l = l * scale + ts;
        m = mn;
        ps[wave][lane] = pj;

        // ---- PV: lane = output dim d; scalar reads conflict-free
        float pv0 = 0.f, pv1 = 0.f, pv2 = 0.f, pv3 = 0.f;
#pragma unroll
        for (int j4 = 0; j4 < 16; ++j4) {
            float4 p4 = *(const float4*)&ps[wave][j4 * 4];   // broadcast
            pv0 = fmaf(p4.x, Vt[dq][j4 * 4 + 0][dk], pv0);
            pv1 = fmaf(p4.y, Vt[dq][j4 * 4 + 1][dk], pv1);
            pv2 = fmaf(p4.z, Vt[dq][j4 * 4 + 2][dk], pv2);
            pv3 = fmaf(p4.w, Vt[dq][j4 * 4 + 3][dk], pv3);
        }
        oacc = oacc * scale + ((pv0 + pv1) + (pv2 + pv3));
    }
    o[qoff + lane] = oacc / l;
}

// ---------------------------------------------------------------------------
// Residual + LayerNorm fp32 (round-0 proven)
__global__ __launch_bounds__(256) void ln_kernel(
    const float* __restrict__ res, const float* __restrict__ y,
    const float* __restrict__ g, const float* __restrict__ b,
    float* __restrict__ outp)
{
    int t = blockIdx.x, tid = threadIdx.x;
    size_t base = (size_t)t * ND;
    float v[4];
    float s = 0.f, s2 = 0.f;
#pragma unroll
    for (int i = 0; i < 4; ++i) {
        int d = tid + 256 * i;
        float val = y[base + d];
        if (res) val += res[base + d];
        v[i] = val;
        s += val;
        s2 += val * val;
    }
    for (int off = 32; off; off >>= 1) {
        s  += __shfl_xor(s, off);
        s2 += __shfl_xor(s2, off);
    }
    __shared__ float rs[4], rs2[4];
    int wave = tid >> 6, lane = tid & 63;
    if (!lane) { rs[wave] = s; rs2[wave] = s2; }
    __syncthreads();
    s = rs[0] + rs[1] + rs[2] + rs[3];
    s2 = rs2[0] + rs2[1] + rs2[2] + rs2[3];
    float mu = s / ND;
    float var = s2 / ND - mu * mu;
    float rstd = rsqrtf(var + 1e-5f);
#pragma unroll
    for (int i = 0; i < 4; ++i) {
        int d = tid + 256 * i;
        outp[base + d] = (v[i] - mu) * rstd * g[d] + b[d];
    }
}

// ---------------------------------------------------------------------------
// MoE gate (round-0 proven)
__global__ __launch_bounds__(256) void gate_kernel(
    const float* __restrict__ x, const float* __restrict__ gw,
    const float* __restrict__ gb, float* __restrict__ we)
{
    int t = blockIdx.x, tid = threadIdx.x;
    float acc[8] = {};
#pragma unroll
    for (int i = 0; i < 4; ++i) {
        int d = tid * 4 + i;
        float xv = x[(size_t)t * ND + d];
#pragma unroll
        for (int e = 0; e < 8; ++e) acc[e] += xv * gw[d * 8 + e];
    }
    for (int off = 32; off; off >>= 1)
#pragma unroll
        for (int e = 0; e < 8; ++e) acc[e] += __shfl_xor(acc[e], off);
    __shared__ float red[4][8];
    int wave = tid >> 6, lane = tid & 63;
    if (!lane)
#pragma unroll
        for (int e = 0; e < 8; ++e) red[wave][e] = acc[e];
    __syncthreads();
    if (tid == 0) {
        float lg[8];
#pragma unroll
        for (int e = 0; e < 8; ++e)
            lg[e] = red[0][e] + red[1][e] + red[2][e] + red[3][e] + gb[e];
        int i1 = 0;
        for (int e = 1; e < 8; ++e) if (lg[e] > lg[i1]) i1 = e;
        int i2 = -1;
        for (int e = 0; e < 8; ++e) if (e != i1 && (i2 < 0 || lg[e] > lg[i2])) i2 = e;
        float e2 = __expf(lg[i2] - lg[i1]);
        float denom = 1.f + e2;
#pragma unroll
        for (int e = 0; e < 8; ++e) we[t * 8 + e] = 0.f;
        we[t * 8 + i1] = 1.f / denom;
        we[t * 8 + i2] = e2 / denom;
    }
}

__global__ void zero_kernel(float* __restrict__ p, int n) {
    int i = blockIdx.x * blockDim.x + threadIdx.x;
    if (i < n) p[i] = 0.f;
}

__global__ void cast_kernel(const float* __restrict__ src, bf16* __restrict__ dst, int n) {
    int i = blockIdx.x * blockDim.x + threadIdx.x;
    if (i < n) dst[i] = f2b(src[i]);
}

// ---------------------------------------------------------------------------
extern "C" void kernel_launch(void* const* d_in, const int* in_sizes, int n_in,
                              void* d_out, int out_size, void* d_ws, size_t ws_size,
                              hipStream_t stream) {
    (void)in_sizes; (void)n_in; (void)out_size; (void)ws_size;
    const int*   src  = (const int*)  d_in[0];
    const float* emb  = (const float*)d_in[1];
    const float* qw   = (const float*)d_in[2];
    const float* qb   = (const float*)d_in[3];
    const float* kw   = (const float*)d_in[4];
    const float* kb   = (const float*)d_in[5];
    const float* vw   = (const float*)d_in[6];
    const float* vb   = (const float*)d_in[7];
    const float* ow   = (const float*)d_in[8];
    const float* ob   = (const float*)d_in[9];
    const float* f1w  = (const float*)d_in[10];
    const float* f1b  = (const float*)d_in[11];
    const float* f2w  = (const float*)d_in[12];
    const float* f2b_ = (const float*)d_in[13];
    const float* ln1g = (const float*)d_in[14];
    const float* ln1b = (const float*)d_in[15];
    const float* ln2g = (const float*)d_in[16];
    const float* ln2b = (const float*)d_in[17];
    const float* gw   = (const float*)d_in[18];
    const float* gb   = (const float*)d_in[19];
    const float* ew1  = (const float*)d_in[20];
    const float* eb1  = (const float*)d_in[21];
    const float* ew2  = (const float*)d_in[22];
    const float* eb2  = (const float*)d_in[23];
    const float* flng = (const float*)d_in[24];
    const float* flnb = (const float*)d_in[25];
    const float* outw = (const float*)d_in[26];
    const float* outb = (const float*)d_in[27];
    float* out = (float*)d_out;

    char* w = (char*)d_ws;
    size_t off = 0;
    auto alloc = [&](size_t bytes) -> char* {
        size_t cur = (off + 255) & ~(size_t)255;
        off = cur + bytes;
        return w + cur;
    };

    // Pre-gate fp32 buffers (round-0 layout). qbuf..hbuf are contiguous:
    // the 64MB span is reused post-gate for the transposed vocab weight.
    float* xbuf  = (float*)alloc((size_t)NT * ND * 4);
    float* qbuf  = (float*)alloc((size_t)NT * ND * 4);      // ┐
    float* kbuf  = (float*)alloc((size_t)NT * ND * 4);      // │ 64MB contiguous
    float* vbuf  = (float*)alloc((size_t)NT * ND * 4);      // │ (dead post-gate)
    float* tbuf  = (float*)alloc((size_t)NT * ND * 4);      // │
    float* hbuf  = (float*)alloc((size_t)NT * NDFF * 4);    // ┘
    float* obuf  = (float*)alloc((size_t)NT * ND * 4);
    float* macc  = (float*)alloc((size_t)NT * ND * 4);
    bf16*  hb    = (bf16*) alloc((size_t)NT * NDFF * 2);
    bf16*  xb    = (bf16*) alloc((size_t)NT * ND * 2);
    bf16*  lnout = (bf16*) alloc((size_t)NT * ND * 2);
    bf16*  e1t   = (bf16*) alloc((size_t)NDFF * ND * 2);
    bf16*  e2t   = (bf16*) alloc((size_t)ND * NDFF * 2);
    float* webuf = (float*)alloc((size_t)NT * NE * 4);
    float* cbuf  = (float*)alloc((size_t)NS * 32 * 4);
    float* snbuf = (float*)alloc((size_t)NS * 32 * 4);
    bf16*  outwt = (bf16*)qbuf;   // [32000][1024] bf16 = 62.5MB in the dead 64MB span

    yarn_kernel<<<(NS * 32) / 256, 256, 0, stream>>>(cbuf, snbuf);
    embed_kernel<<<(NT * ND) / 256, 256, 0, stream>>>(src, emb, xbuf);

    for (int l = 0; l < NL; ++l) {
        const float* qwl = qw + (size_t)l * ND * ND;
        const float* kwl = kw + (size_t)l * ND * ND;
        const float* vwl = vw + (size_t)l * ND * ND;
        const float* owl = ow + (size_t)l * ND * ND;
        dim3 gdd(ND / BN, NT / BM);
        gemm_kernel<false><<<gdd, 256, 0, stream>>>(xbuf, qwl, qb + l * ND, qbuf, NT, ND, ND);
        gemm_kernel<false><<<gdd, 256, 0, stream>>>(xbuf, kwl, kb + l * ND, kbuf, NT, ND, ND);
        gemm_kernel<false><<<gdd, 256, 0, stream>>>(xbuf, vwl, vb + l * ND, vbuf, NT, ND, ND);
        rope_kernel<<<(NT * NH * 32) / 256, 256, 0, stream>>>(qbuf, kbuf, cbuf, snbuf);
        attn_kernel<<<NB * NH * (NS / 4), 256, 0, stream>>>(qbuf, kbuf, vbuf, obuf);
        gemm_kernel<false><<<gdd, 256, 0, stream>>>(obuf, owl, ob + l * ND, tbuf, NT, ND, ND);
        ln_kernel<<<NT, 256, 0, stream>>>(xbuf, tbuf, ln1g + l * ND, ln1b + l * ND, xbuf);
        gemm_kernel<true><<<dim3(NDFF / BN, NT / BM), 256, 0, stream>>>(
            xbuf, f1w + (size_t)l * ND * NDFF, f1b + l * NDFF, hbuf, NT, NDFF, ND);
        gemm_kernel<false><<<gdd, 256, 0, stream>>>(
            hbuf, f2w + (size_t)l * NDFF * ND, f2b_ + l * ND, tbuf, NT, ND, NDFF);
        ln_kernel<<<NT, 256, 0, stream>>>(xbuf, tbuf, ln2g + l * ND, ln2b + l * ND, xbuf);
    }

    // Gate on exact fp32 x (decisions match reference)
    gate_kernel<<<NT, 256, 0, stream>>>(xbuf, gw, gb, webuf);

    // Post-gate: decision-free compute on bf16 MFMA
    cast_kernel<<<(NT * ND) / 256, 256, 0, stream>>>(xbuf, xb, NT * ND);
    zero_kernel<<<(NT * ND) / 256, 256, 0, stream>>>(macc, NT * ND);
    wtconv_kernel<<<dim3(1000, 32), 256, 0, stream>>>(outw, outwt, 1024, 32000);
    for (int e = 0; e < NE; ++e) {
        wtconv_kernel<<<dim3(128, 32), 256, 0, stream>>>(ew1 + (size_t)e * 4194304, e1t, 1024, 4096);
        wtconv_kernel<<<dim3(32, 128), 256, 0, stream>>>(ew2 + (size_t)e * 4194304, e2t, 4096, 1024);
        mm_kernel<1><<<dim3(32, 16), 256, 0, stream>>>(xb, e1t, eb1 + e * 4096, hb, nullptr, NT, 4096, 1024);
        mm_kernel<3><<<dim3(8, 16), 256, 0, stream>>>(hb, e2t, eb2 + e * 1024, macc, webuf + e, NT, 1024, 4096);
    }
    ln_kernel<<<NT, 256, 0, stream>>>(nullptr, macc, flng, flnb, obuf);
    cast_kernel<<<(NT * ND) / 256, 256, 0, stream>>>(obuf, lnout, NT * ND);
    mm_kernel<0><<<dim3(250, 16), 256, 0, stream>>>(lnout, outwt, outb, out, nullptr, NT, NV, 1024);
}

// Round 8
// 4996.872 us; speedup vs baseline: 3.1953x; 1.0676x over previous
//
#include <hip/hip_runtime.h>
#include <hip/hip_bf16.h>
#include <math.h>

constexpr int NV = 32000, ND = 1024, NH = 16, NHD = 64, NL = 3, NDFF = 4096;
constexpr int NE = 8, NB = 2, NS = 1024, NT = NB * NS;

typedef __attribute__((ext_vector_type(8))) short bf16x8;
typedef __attribute__((ext_vector_type(8))) _Float16 f16x8;
typedef __attribute__((ext_vector_type(4))) float f32x4;
typedef __hip_bfloat16 bf16;

__device__ __forceinline__ bf16 f2b(float v) { return __float2bfloat16(v); }

// ---------------------------------------------------------------------------
// YaRN cos/sin table (round-0 proven)
__global__ void yarn_kernel(float* __restrict__ c, float* __restrict__ sn) {
    int idx = blockIdx.x * blockDim.x + threadIdx.x;   // NS*32 threads
    int j = idx & 31;
    int s = idx >> 5;
    double ex = (double)(2 * j) / 64.0;
    double fe = 1.0 / pow(10000.0, ex);
    double fi = fe / 8.0;
    double lin = ((double)j - 8.0) / 13.0;
    double mask = 1.0 - fmin(fmax(lin, 0.0), 1.0);
    double invf = fi * (1.0 - mask) + fe * mask;
    double ms = 0.1 * log(8.0) + 1.0;
    double fr = (double)s * invf;
    c[idx]  = (float)(cos(fr) * ms);
    sn[idx] = (float)(sin(fr) * ms);
}

// ---------------------------------------------------------------------------
__global__ void embed_kernel(const int* __restrict__ src, const float* __restrict__ emb,
                             float* __restrict__ x) {
    int idx = blockIdx.x * blockDim.x + threadIdx.x;   // NT*ND threads
    int t = idx >> 10;
    int d = idx & 1023;
    int s = src[t];
    s = s < 0 ? 0 : (s > NV - 1 ? NV - 1 : s);
    x[idx] = emb[(size_t)s * ND + d] * 32.0f;          // sqrt(1024)=32
}

// ---------------------------------------------------------------------------
// Split fp32 -> fp16 hi + fp16 lo (optionally with ReLU first)
template<bool RELU>
__global__ void splitf_kernel(const float* __restrict__ src,
                              _Float16* __restrict__ dh, _Float16* __restrict__ dl, int n) {
    int i = blockIdx.x * blockDim.x + threadIdx.x;
    if (i >= n) return;
    float v = src[i];
    if (RELU) v = fmaxf(v, 0.f);
    _Float16 h = (_Float16)v;
    dh[i] = h;
    dl[i] = (_Float16)(v - (float)h);
}

// ---------------------------------------------------------------------------
// Transpose+split: src fp32 [K][N] -> dst fp16 hi/lo [N][K]
__global__ __launch_bounds__(256) void wtconvh_kernel(
    const float* __restrict__ src, _Float16* __restrict__ dh, _Float16* __restrict__ dl,
    int K, int N)
{
    __shared__ float tile[32][33];
    int n0 = blockIdx.x * 32, k0 = blockIdx.y * 32;
    int tx = threadIdx.x & 31, ty = threadIdx.x >> 5;   // ty 0..7
#pragma unroll
    for (int i = 0; i < 4; ++i)
        tile[ty + 8 * i][tx] = src[(size_t)(k0 + ty + 8 * i) * N + n0 + tx];
    __syncthreads();
#pragma unroll
    for (int i = 0; i < 4; ++i) {
        float v = tile[tx][ty + 8 * i];
        _Float16 h = (_Float16)v;
        size_t idx = (size_t)(n0 + ty + 8 * i) * K + k0 + tx;
        dh[idx] = h;
        dl[idx] = (_Float16)(v - (float)h);
    }
}

// ---------------------------------------------------------------------------
// Transpose+convert: src fp32 [K][N] -> dst bf16 [N][K]  (post-gate path)
__global__ __launch_bounds__(256) void wtconv_kernel(
    const float* __restrict__ src, bf16* __restrict__ dst, int K, int N)
{
    __shared__ float tile[32][33];
    int n0 = blockIdx.x * 32, k0 = blockIdx.y * 32;
    int tx = threadIdx.x & 31, ty = threadIdx.x >> 5;
#pragma unroll
    for (int i = 0; i < 4; ++i)
        tile[ty + 8 * i][tx] = src[(size_t)(k0 + ty + 8 * i) * N + n0 + tx];
    __syncthreads();
#pragma unroll
    for (int i = 0; i < 4; ++i)
        dst[(size_t)(n0 + ty + 8 * i) * K + k0 + tx] = f2b(tile[tx][ty + 8 * i]);
}

// ---------------------------------------------------------------------------
// fp16 MFMA GEMM pass (split-precision building block), proven mm geometry.
// ACC=0: C = A@BT^T + bias ; ACC=1: C += A@BT^T (bias ignored)
template<int ACC>
__global__ __launch_bounds__(256) void mmh_kernel(
    const _Float16* __restrict__ A, const _Float16* __restrict__ BT,
    const float* __restrict__ bias, float* __restrict__ C,
    int M, int N, int K)
{
    __shared__ char smem[32768];
    const int tid = threadIdx.x;
    const int lane = tid & 63, wave = tid >> 6;
    const int wm = wave >> 1, wn = wave & 1;
    const int bm = blockIdx.y * 128, bn = blockIdx.x * 128;
    const int l15 = lane & 15, l4 = lane >> 4;
    const int srow = tid >> 3;
    const int sc = tid & 7;

    f32x4 acc[4][4];
#pragma unroll
    for (int i = 0; i < 4; ++i)
#pragma unroll
        for (int j = 0; j < 4; ++j) acc[i][j] = 0.f;

    for (int k0 = 0; k0 < K; k0 += 64) {
#pragma unroll
        for (int p = 0; p < 4; ++p) {
            int row = p * 32 + srow;
            int swc = (sc ^ (row & 7)) << 4;
            f16x8 av = *(const f16x8*)(A + (size_t)(bm + row) * K + k0 + sc * 8);
            f16x8 bv = *(const f16x8*)(BT + (size_t)(bn + row) * K + k0 + sc * 8);
            *(f16x8*)(smem + row * 128 + swc) = av;
            *(f16x8*)(smem + 16384 + row * 128 + swc) = bv;
        }
        __syncthreads();
#pragma unroll
        for (int kk = 0; kk < 2; ++kk) {
            f16x8 af[4], bfv[4];
            int g = kk * 4 + l4;
#pragma unroll
            for (int mi = 0; mi < 4; ++mi) {
                int row = wm * 64 + mi * 16 + l15;
                af[mi] = *(const f16x8*)(smem + row * 128 + ((g ^ (row & 7)) << 4));
            }
#pragma unroll
            for (int ni = 0; ni < 4; ++ni) {
                int row = wn * 64 + ni * 16 + l15;
                bfv[ni] = *(const f16x8*)(smem + 16384 + row * 128 + ((g ^ (row & 7)) << 4));
            }
#pragma unroll
            for (int mi = 0; mi < 4; ++mi)
#pragma unroll
                for (int ni = 0; ni < 4; ++ni)
                    acc[mi][ni] = __builtin_amdgcn_mfma_f32_16x16x32_f16(
                        af[mi], bfv[ni], acc[mi][ni], 0, 0, 0);
        }
        __syncthreads();
    }
#pragma unroll
    for (int ni = 0; ni < 4; ++ni) {
        int col = bn + wn * 64 + ni * 16 + l15;
        float bv = ACC ? 0.f : bias[col];
#pragma unroll
        for (int mi = 0; mi < 4; ++mi) {
#pragma unroll
            for (int rr = 0; rr < 4; ++rr) {
                int row = bm + wm * 64 + mi * 16 + l4 * 4 + rr;
                size_t idx = (size_t)row * N + col;
                if (ACC) C[idx] += acc[mi][ni][rr];
                else     C[idx] = acc[mi][ni][rr] + bv;
            }
        }
    }
}

// ---------------------------------------------------------------------------
// bf16 MFMA GEMM (proven): post-gate path.
// EPI: 0=f32 store, 1=bf16 relu store, 3=f32 acc += rowscale*(v+bias)
template<int EPI>
__global__ __launch_bounds__(256) void mm_kernel(
    const bf16* __restrict__ A, const bf16* __restrict__ BT,
    const float* __restrict__ bias, void* __restrict__ Cp,
    const float* __restrict__ rowscale, int M, int N, int K)
{
    __shared__ char smem[32768];
    const int tid = threadIdx.x;
    const int lane = tid & 63, wave = tid >> 6;
    const int wm = wave >> 1, wn = wave & 1;
    const int bm = blockIdx.y * 128, bn = blockIdx.x * 128;
    const int l15 = lane & 15, l4 = lane >> 4;
    const int srow = tid >> 3;
    const int sc = tid & 7;

    f32x4 acc[4][4];
#pragma unroll
    for (int i = 0; i < 4; ++i)
#pragma unroll
        for (int j = 0; j < 4; ++j) acc[i][j] = 0.f;

    for (int k0 = 0; k0 < K; k0 += 64) {
#pragma unroll
        for (int p = 0; p < 4; ++p) {
            int row = p * 32 + srow;
            int swc = (sc ^ (row & 7)) << 4;
            bf16x8 av = *(const bf16x8*)(A + (size_t)(bm + row) * K + k0 + sc * 8);
            bf16x8 bv = *(const bf16x8*)(BT + (size_t)(bn + row) * K + k0 + sc * 8);
            *(bf16x8*)(smem + row * 128 + swc) = av;
            *(bf16x8*)(smem + 16384 + row * 128 + swc) = bv;
        }
        __syncthreads();
#pragma unroll
        for (int kk = 0; kk < 2; ++kk) {
            bf16x8 af[4], bfv[4];
            int g = kk * 4 + l4;
#pragma unroll
            for (int mi = 0; mi < 4; ++mi) {
                int row = wm * 64 + mi * 16 + l15;
                af[mi] = *(const bf16x8*)(smem + row * 128 + ((g ^ (row & 7)) << 4));
            }
#pragma unroll
            for (int ni = 0; ni < 4; ++ni) {
                int row = wn * 64 + ni * 16 + l15;
                bfv[ni] = *(const bf16x8*)(smem + 16384 + row * 128 + ((g ^ (row & 7)) << 4));
            }
#pragma unroll
            for (int mi = 0; mi < 4; ++mi)
#pragma unroll
                for (int ni = 0; ni < 4; ++ni)
                    acc[mi][ni] = __builtin_amdgcn_mfma_f32_16x16x32_bf16(
                        af[mi], bfv[ni], acc[mi][ni], 0, 0, 0);
        }
        __syncthreads();
    }
#pragma unroll
    for (int ni = 0; ni < 4; ++ni) {
        int col = bn + wn * 64 + ni * 16 + l15;
        float bv = bias[col];
#pragma unroll
        for (int mi = 0; mi < 4; ++mi) {
#pragma unroll
            for (int rr = 0; rr < 4; ++rr) {
                int row = bm + wm * 64 + mi * 16 + l4 * 4 + rr;
                float v = acc[mi][ni][rr] + bv;
                if (EPI == 1) v = fmaxf(v, 0.f);
                if (EPI == 0)
                    ((float*)Cp)[(size_t)row * N + col] = v;
                else if (EPI == 3)
                    ((float*)Cp)[(size_t)row * N + col] += rowscale[(size_t)row * 8] * v;
                else
                    ((bf16*)Cp)[(size_t)row * N + col] = f2b(v);
            }
        }
    }
}

// ---------------------------------------------------------------------------
// RoPE in-place on fp32 q and k (round-0 proven)
__global__ void rope_kernel(float* __restrict__ q, float* __restrict__ k,
                            const float* __restrict__ c, const float* __restrict__ sn) {
    int idx = blockIdx.x * blockDim.x + threadIdx.x;   // NT*NH*32 threads
    int j = idx & 31;
    int h = (idx >> 5) & 15;
    int t = idx >> 9;
    int s = t & (NS - 1);
    float cv = c[s * 32 + j], sv = sn[s * 32 + j];
    size_t base = (size_t)t * ND + h * 64;
    float q1 = q[base + j], q2 = q[base + 32 + j];
    q[base + j]      = q1 * cv - q2 * sv;
    q[base + 32 + j] = q2 * cv + q1 * sv;
    float k1 = k[base + j], k2 = k[base + 32 + j];
    k[base + j]      = k1 * cv - k2 * sv;
    k[base + 32 + j] = k2 * cv + k1 * sv;
}

// ---------------------------------------------------------------------------
// Parallel-key fp32 attention, conflict-free LDS, XCD-aware block decode:
// xcd = i&7 owns 4 heads -> K+V (2MB) fits that XCD's L2.
__global__ __launch_bounds__(256) void attn_kernel(
    const float* __restrict__ q, const float* __restrict__ k,
    const float* __restrict__ v, float* __restrict__ o)
{
    __shared__ float Kt[16][65][4];
    __shared__ float Vt[16][65][4];
    __shared__ float qs[4][64];
    __shared__ float ps[4][64];

    int i = blockIdx.x;                // 8192 blocks
    int xcd = i & 7;
    int s0 = i >> 3;                   // 0..1023
    int bh = xcd * 4 + (s0 >> 8);      // 4 heads per XCD
    int rt = s0 & 255;
    int b = bh >> 4, h = bh & 15;
    int wave = threadIdx.x >> 6, lane = threadIdx.x & 63;
    int r = rt * 4 + wave;
    size_t qoff = ((size_t)(b * NS + r)) * ND + h * 64;
    qs[wave][lane] = q[qoff + lane] * 0.125f;

    const int dq = lane >> 2, dk = lane & 3;

    float m = -1e30f, l = 0.f, oacc = 0.f;

    for (int kt = 0; kt < NS / 64; ++kt) {
        __syncthreads();
#pragma unroll
        for (int p = 0; p < 4; ++p) {
            int row = p * 16 + (threadIdx.x >> 4);
            int f4 = threadIdx.x & 15;
            size_t gg = ((size_t)(b * NS + kt * 64 + row)) * ND + h * 64 + f4 * 4;
            float4 kv = *(const float4*)(k + gg);
            float4 vv = *(const float4*)(v + gg);
            *(float4*)&Kt[f4][row][0] = kv;
            *(float4*)&Vt[f4][row][0] = vv;
        }
        __syncthreads();

        float sa0 = 0.f, sa1 = 0.f, sa2 = 0.f, sa3 = 0.f;
#pragma unroll
        for (int dd = 0; dd < 16; dd += 4) {
            float4 q0 = *(const float4*)&qs[wave][(dd + 0) * 4];
            float4 k0v = *(const float4*)&Kt[dd + 0][lane][0];
            sa0 = fmaf(q0.x, k0v.x, fmaf(q0.y, k0v.y, fmaf(q0.z, k0v.z, fmaf(q0.w, k0v.w, sa0))));
            float4 q1 = *(const float4*)&qs[wave][(dd + 1) * 4];
            float4 k1v = *(const float4*)&Kt[dd + 1][lane][0];
            sa1 = fmaf(q1.x, k1v.x, fmaf(q1.y, k1v.y, fmaf(q1.z, k1v.z, fmaf(q1.w, k1v.w, sa1))));
            float4 q2 = *(const float4*)&qs[wave][(dd + 2) * 4];
            float4 k2v = *(const float4*)&Kt[dd + 2][lane][0];
            sa2 = fmaf(q2.x, k2v.x, fmaf(q2.y, k2v.y, fmaf(q2.z, k2v.z, fmaf(q2.w, k2v.w, sa2))));
            float4 q3 = *(const float4*)&qs[wave][(dd + 3) * 4];
            float4 k3v = *(const float4*)&Kt[dd + 3][lane][0];
            sa3 = fmaf(q3.x, k3v.x, fmaf(q3.y, k3v.y, fmaf(q3.z, k3v.z, fmaf(q3.w, k3v.w, sa3))));
        }
        float s = (sa0 + sa1) + (sa2 + sa3);

        float mt = s;
#pragma unroll
        for (int off2 = 32; off2; off2 >>= 1) mt = fmaxf(mt, __shfl_xor(mt, off2));
        float mn = fmaxf(m, mt);
        float pj = __expf(s - mn);
        float ts = pj;
#pragma unroll
        for (int off2 = 32; off2; off2 >>= 1) ts += __shfl_xor(ts, off2);
        float scale = __expf(m - mn);
        l = l * scale + ts;
        m = mn;
        ps[wave][lane] = pj;

        float pv0 = 0.f, pv1 = 0.f, pv2 = 0.f, pv3 = 0.f;
#pragma unroll
        for (int j4 = 0; j4 < 16; ++j4) {
            float4 p4 = *(const float4*)&ps[wave][j4 * 4];
            pv0 = fmaf(p4.x, Vt[dq][j4 * 4 + 0][dk], pv0);
            pv1 = fmaf(p4.y, Vt[dq][j4 * 4 + 1][dk], pv1);
            pv2 = fmaf(p4.z, Vt[dq][j4 * 4 + 2][dk], pv2);
            pv3 = fmaf(p4.w, Vt[dq][j4 * 4 + 3][dk], pv3);
        }
        oacc = oacc * scale + ((pv0 + pv1) + (pv2 + pv3));
    }
    o[qoff + lane] = oacc / l;
}

// ---------------------------------------------------------------------------
// Residual + LayerNorm fp32 (round-0 proven)
__global__ __launch_bounds__(256) void ln_kernel(
    const float* __restrict__ res, const float* __restrict__ y,
    const float* __restrict__ g, const float* __restrict__ b,
    float* __restrict__ outp)
{
    int t = blockIdx.x, tid = threadIdx.x;
    size_t base = (size_t)t * ND;
    float v[4];
    float s = 0.f, s2 = 0.f;
#pragma unroll
    for (int i = 0; i < 4; ++i) {
        int d = tid + 256 * i;
        float val = y[base + d];
        if (res) val += res[base + d];
        v[i] = val;
        s += val;
        s2 += val * val;
    }
    for (int off = 32; off; off >>= 1) {
        s  += __shfl_xor(s, off);
        s2 += __shfl_xor(s2, off);
    }
    __shared__ float rs[4], rs2[4];
    int wave = tid >> 6, lane = tid & 63;
    if (!lane) { rs[wave] = s; rs2[wave] = s2; }
    __syncthreads();
    s = rs[0] + rs[1] + rs[2] + rs[3];
    s2 = rs2[0] + rs2[1] + rs2[2] + rs2[3];
    float mu = s / ND;
    float var = s2 / ND - mu * mu;
    float rstd = rsqrtf(var + 1e-5f);
#pragma unroll
    for (int i = 0; i < 4; ++i) {
        int d = tid + 256 * i;
        outp[base + d] = (v[i] - mu) * rstd * g[d] + b[d];
    }
}

// ---------------------------------------------------------------------------
// MoE gate (round-0 proven)
__global__ __launch_bounds__(256) void gate_kernel(
    const float* __restrict__ x, const float* __restrict__ gw,
    const float* __restrict__ gb, float* __restrict__ we)
{
    int t = blockIdx.x, tid = threadIdx.x;
    float acc[8] = {};
#pragma unroll
    for (int i = 0; i < 4; ++i) {
        int d = tid * 4 + i;
        float xv = x[(size_t)t * ND + d];
#pragma unroll
        for (int e = 0; e < 8; ++e) acc[e] += xv * gw[d * 8 + e];
    }
    for (int off = 32; off; off >>= 1)
#pragma unroll
        for (int e = 0; e < 8; ++e) acc[e] += __shfl_xor(acc[e], off);
    __shared__ float red[4][8];
    int wave = tid >> 6, lane = tid & 63;
    if (!lane)
#pragma unroll
        for (int e = 0; e < 8; ++e) red[wave][e] = acc[e];
    __syncthreads();
    if (tid == 0) {
        float lg[8];
#pragma unroll
        for (int e = 0; e < 8; ++e)
            lg[e] = red[0][e] + red[1][e] + red[2][e] + red[3][e] + gb[e];
        int i1 = 0;
        for (int e = 1; e < 8; ++e) if (lg[e] > lg[i1]) i1 = e;
        int i2 = -1;
        for (int e = 0; e < 8; ++e) if (e != i1 && (i2 < 0 || lg[e] > lg[i2])) i2 = e;
        float e2 = __expf(lg[i2] - lg[i1]);
        float denom = 1.f + e2;
#pragma unroll
        for (int e = 0; e < 8; ++e) we[t * 8 + e] = 0.f;
        we[t * 8 + i1] = 1.f / denom;
        we[t * 8 + i2] = e2 / denom;
    }
}

__global__ void zero_kernel(float* __restrict__ p, int n) {
    int i = blockIdx.x * blockDim.x + threadIdx.x;
    if (i < n) p[i] = 0.f;
}

__global__ void cast_kernel(const float* __restrict__ src, bf16* __restrict__ dst, int n) {
    int i = blockIdx.x * blockDim.x + threadIdx.x;
    if (i < n) dst[i] = f2b(src[i]);
}

// ---------------------------------------------------------------------------
extern "C" void kernel_launch(void* const* d_in, const int* in_sizes, int n_in,
                              void* d_out, int out_size, void* d_ws, size_t ws_size,
                              hipStream_t stream) {
    (void)in_sizes; (void)n_in; (void)out_size; (void)ws_size;
    const int*   src  = (const int*)  d_in[0];
    const float* emb  = (const float*)d_in[1];
    const float* qw   = (const float*)d_in[2];
    const float* qb   = (const float*)d_in[3];
    const float* kw   = (const float*)d_in[4];
    const float* kb   = (const float*)d_in[5];
    const float* vw   = (const float*)d_in[6];
    const float* vb   = (const float*)d_in[7];
    const float* ow   = (const float*)d_in[8];
    const float* ob   = (const float*)d_in[9];
    const float* f1w  = (const float*)d_in[10];
    const float* f1b  = (const float*)d_in[11];
    const float* f2w  = (const float*)d_in[12];
    const float* f2b_ = (const float*)d_in[13];
    const float* ln1g = (const float*)d_in[14];
    const float* ln1b = (const float*)d_in[15];
    const float* ln2g = (const float*)d_in[16];
    const float* ln2b = (const float*)d_in[17];
    const float* gw   = (const float*)d_in[18];
    const float* gb   = (const float*)d_in[19];
    const float* ew1  = (const float*)d_in[20];
    const float* eb1  = (const float*)d_in[21];
    const float* ew2  = (const float*)d_in[22];
    const float* eb2  = (const float*)d_in[23];
    const float* flng = (const float*)d_in[24];
    const float* flnb = (const float*)d_in[25];
    const float* outw = (const float*)d_in[26];
    const float* outb = (const float*)d_in[27];
    float* out = (float*)d_out;

    char* w = (char*)d_ws;
    size_t off = 0;
    auto alloc = [&](size_t bytes) -> char* {
        size_t cur = (off + 255) & ~(size_t)255;
        off = cur + bytes;
        return w + cur;
    };

    // fp32 buffers; qbuf..hbuf contiguous 64MB reused post-gate for outwt.
    float* xbuf  = (float*)alloc((size_t)NT * ND * 4);
    float* qbuf  = (float*)alloc((size_t)NT * ND * 4);      // ┐
    float* kbuf  = (float*)alloc((size_t)NT * ND * 4);      // │ 64MB contiguous
    float* vbuf  = (float*)alloc((size_t)NT * ND * 4);      // │ (dead post-gate)
    float* tbuf  = (float*)alloc((size_t)NT * ND * 4);      // │
    float* hbuf  = (float*)alloc((size_t)NT * NDFF * 4);    // ┘
    float* obuf  = (float*)alloc((size_t)NT * ND * 4);
    float* macc  = (float*)alloc((size_t)NT * ND * 4);
    // fp16 split activations
    _Float16* xh = (_Float16*)alloc((size_t)NT * ND * 2);
    _Float16* xl = (_Float16*)alloc((size_t)NT * ND * 2);
    _Float16* oh = (_Float16*)alloc((size_t)NT * ND * 2);
    _Float16* ol = (_Float16*)alloc((size_t)NT * ND * 2);
    _Float16* hh = (_Float16*)alloc((size_t)NT * NDFF * 2);
    _Float16* hl = (_Float16*)alloc((size_t)NT * NDFF * 2);
    // fp16 split weights (per-layer reuse)
    _Float16* wqh = (_Float16*)alloc((size_t)ND * ND * 2);
    _Float16* wql = (_Float16*)alloc((size_t)ND * ND * 2);
    _Float16* wkh = (_Float16*)alloc((size_t)ND * ND * 2);
    _Float16* wkl = (_Float16*)alloc((size_t)ND * ND * 2);
    _Float16* wvh = (_Float16*)alloc((size_t)ND * ND * 2);
    _Float16* wvl = (_Float16*)alloc((size_t)ND * ND * 2);
    _Float16* woh = (_Float16*)alloc((size_t)ND * ND * 2);
    _Float16* wol = (_Float16*)alloc((size_t)ND * ND * 2);
    _Float16* w1h = (_Float16*)alloc((size_t)ND * NDFF * 2);
    _Float16* w1l = (_Float16*)alloc((size_t)ND * NDFF * 2);
    _Float16* w2h = (_Float16*)alloc((size_t)ND * NDFF * 2);
    _Float16* w2l = (_Float16*)alloc((size_t)ND * NDFF * 2);
    // bf16 post-gate
    bf16*  hb    = (bf16*) alloc((size_t)NT * NDFF * 2);
    bf16*  xb    = (bf16*) alloc((size_t)NT * ND * 2);
    bf16*  lnout = (bf16*) alloc((size_t)NT * ND * 2);
    bf16*  e1t   = (bf16*) alloc((size_t)NDFF * ND * 2);
    bf16*  e2t   = (bf16*) alloc((size_t)ND * NDFF * 2);
    float* webuf = (float*)alloc((size_t)NT * NE * 4);
    float* cbuf  = (float*)alloc((size_t)NS * 32 * 4);
    float* snbuf = (float*)alloc((size_t)NS * 32 * 4);
    bf16*  outwt = (bf16*)qbuf;   // 62.5MB in the dead 64MB span

    yarn_kernel<<<(NS * 32) / 256, 256, 0, stream>>>(cbuf, snbuf);
    embed_kernel<<<(NT * ND) / 256, 256, 0, stream>>>(src, emb, xbuf);
    splitf_kernel<false><<<(NT * ND) / 256, 256, 0, stream>>>(xbuf, xh, xl, NT * ND);

    const int NX = NT * ND;
    dim3 gdd(ND / 128, NT / 128);       // N=1024 GEMMs
    dim3 gdf(NDFF / 128, NT / 128);     // N=4096 GEMMs

    for (int l = 0; l < NL; ++l) {
        wtconvh_kernel<<<dim3(32, 32), 256, 0, stream>>>(qw + (size_t)l * 1048576, wqh, wql, 1024, 1024);
        wtconvh_kernel<<<dim3(32, 32), 256, 0, stream>>>(kw + (size_t)l * 1048576, wkh, wkl, 1024, 1024);
        wtconvh_kernel<<<dim3(32, 32), 256, 0, stream>>>(vw + (size_t)l * 1048576, wvh, wvl, 1024, 1024);
        wtconvh_kernel<<<dim3(32, 32), 256, 0, stream>>>(ow + (size_t)l * 1048576, woh, wol, 1024, 1024);
        wtconvh_kernel<<<dim3(128, 32), 256, 0, stream>>>(f1w + (size_t)l * 4194304, w1h, w1l, 1024, 4096);
        wtconvh_kernel<<<dim3(32, 128), 256, 0, stream>>>(f2w + (size_t)l * 4194304, w2h, w2l, 4096, 1024);

        // QKV: 3-term split GEMMs -> fp32
        mmh_kernel<0><<<gdd, 256, 0, stream>>>(xh, wqh, qb + l * 1024, qbuf, NT, 1024, 1024);
        mmh_kernel<1><<<gdd, 256, 0, stream>>>(xh, wql, nullptr, qbuf, NT, 1024, 1024);
        mmh_kernel<1><<<gdd, 256, 0, stream>>>(xl, wqh, nullptr, qbuf, NT, 1024, 1024);
        mmh_kernel<0><<<gdd, 256, 0, stream>>>(xh, wkh, kb + l * 1024, kbuf, NT, 1024, 1024);
        mmh_kernel<1><<<gdd, 256, 0, stream>>>(xh, wkl, nullptr, kbuf, NT, 1024, 1024);
        mmh_kernel<1><<<gdd, 256, 0, stream>>>(xl, wkh, nullptr, kbuf, NT, 1024, 1024);
        mmh_kernel<0><<<gdd, 256, 0, stream>>>(xh, wvh, vb + l * 1024, vbuf, NT, 1024, 1024);
        mmh_kernel<1><<<gdd, 256, 0, stream>>>(xh, wvl, nullptr, vbuf, NT, 1024, 1024);
        mmh_kernel<1><<<gdd, 256, 0, stream>>>(xl, wvh, nullptr, vbuf, NT, 1024, 1024);

        rope_kernel<<<(NT * NH * 32) / 256, 256, 0, stream>>>(qbuf, kbuf, cbuf, snbuf);
        attn_kernel<<<NB * NH * (NS / 4), 256, 0, stream>>>(qbuf, kbuf, vbuf, obuf);
        splitf_kernel<false><<<NX / 256, 256, 0, stream>>>(obuf, oh, ol, NX);

        mmh_kernel<0><<<gdd, 256, 0, stream>>>(oh, woh, ob + l * 1024, tbuf, NT, 1024, 1024);
        mmh_kernel<1><<<gdd, 256, 0, stream>>>(oh, wol, nullptr, tbuf, NT, 1024, 1024);
        mmh_kernel<1><<<gdd, 256, 0, stream>>>(ol, woh, nullptr, tbuf, NT, 1024, 1024);

        ln_kernel<<<NT, 256, 0, stream>>>(xbuf, tbuf, ln1g + l * 1024, ln1b + l * 1024, xbuf);
        splitf_kernel<false><<<NX / 256, 256, 0, stream>>>(xbuf, xh, xl, NX);

        mmh_kernel<0><<<gdf, 256, 0, stream>>>(xh, w1h, f1b + l * 4096, hbuf, NT, 4096, 1024);
        mmh_kernel<1><<<gdf, 256, 0, stream>>>(xh, w1l, nullptr, hbuf, NT, 4096, 1024);
        mmh_kernel<1><<<gdf, 256, 0, stream>>>(xl, w1h, nullptr, hbuf, NT, 4096, 1024);
        splitf_kernel<true><<<(NT * NDFF) / 256, 256, 0, stream>>>(hbuf, hh, hl, NT * NDFF);

        mmh_kernel<0><<<gdd, 256, 0, stream>>>(hh, w2h, f2b_ + l * 1024, tbuf, NT, 1024, 4096);
        mmh_kernel<1><<<gdd, 256, 0, stream>>>(hh, w2l, nullptr, tbuf, NT, 1024, 4096);
        mmh_kernel<1><<<gdd, 256, 0, stream>>>(hl, w2h, nullptr, tbuf, NT, 1024, 4096);

        ln_kernel<<<NT, 256, 0, stream>>>(xbuf, tbuf, ln2g + l * 1024, ln2b + l * 1024, xbuf);
        splitf_kernel<false><<<NX / 256, 256, 0, stream>>>(xbuf, xh, xl, NX);
    }

    // Gate on exact fp32 x (decisions match reference)
    gate_kernel<<<NT, 256, 0, stream>>>(xbuf, gw, gb, webuf);

    // Post-gate: decision-free compute on bf16 MFMA (round-5 proven)
    cast_kernel<<<NX / 256, 256, 0, stream>>>(xbuf, xb, NX);
    zero_kernel<<<NX / 256, 256, 0, stream>>>(macc, NX);
    wtconv_kernel<<<dim3(1000, 32), 256, 0, stream>>>(outw, outwt, 1024, 32000);
    for (int e = 0; e < NE; ++e) {
        wtconv_kernel<<<dim3(128, 32), 256, 0, stream>>>(ew1 + (size_t)e * 4194304, e1t, 1024, 4096);
        wtconv_kernel<<<dim3(32, 128), 256, 0, stream>>>(ew2 + (size_t)e * 4194304, e2t, 4096, 1024);
        mm_kernel<1><<<dim3(32, 16), 256, 0, stream>>>(xb, e1t, eb1 + e * 4096, hb, nullptr, NT, 4096, 1024);
        mm_kernel<3><<<dim3(8, 16), 256, 0, stream>>>(hb, e2t, eb2 + e * 1024, macc, webuf + e, NT, 1024, 4096);
    }
    ln_kernel<<<NT, 256, 0, stream>>>(nullptr, macc, flng, flnb, obuf);
    cast_kernel<<<NX / 256, 256, 0, stream>>>(obuf, lnout, NX);
    mm_kernel<0><<<dim3(250, 16), 256, 0, stream>>>(lnout, outwt, outb, out, nullptr, NT, NV, 1024);
}

// Round 9
// 2792.072 us; speedup vs baseline: 5.7186x; 1.7897x over previous
//
#include <hip/hip_runtime.h>
#include <hip/hip_bf16.h>
#include <math.h>

constexpr int NV = 32000, ND = 1024, NH = 16, NHD = 64, NL = 3, NDFF = 4096;
constexpr int NE = 8, NB = 2, NS = 1024, NT = NB * NS;

typedef __attribute__((ext_vector_type(8))) short bf16x8;
typedef __attribute__((ext_vector_type(8))) _Float16 f16x8;
typedef __attribute__((ext_vector_type(4))) float f32x4;
typedef __hip_bfloat16 bf16;

__device__ __forceinline__ bf16 f2b(float v) { return __float2bfloat16(v); }

// ---------------------------------------------------------------------------
__global__ void yarn_kernel(float* __restrict__ c, float* __restrict__ sn) {
    int idx = blockIdx.x * blockDim.x + threadIdx.x;   // NS*32 threads
    int j = idx & 31;
    int s = idx >> 5;
    double ex = (double)(2 * j) / 64.0;
    double fe = 1.0 / pow(10000.0, ex);
    double fi = fe / 8.0;
    double lin = ((double)j - 8.0) / 13.0;
    double mask = 1.0 - fmin(fmax(lin, 0.0), 1.0);
    double invf = fi * (1.0 - mask) + fe * mask;
    double ms = 0.1 * log(8.0) + 1.0;
    double fr = (double)s * invf;
    c[idx]  = (float)(cos(fr) * ms);
    sn[idx] = (float)(sin(fr) * ms);
}

// ---------------------------------------------------------------------------
__global__ void embed_kernel(const int* __restrict__ src, const float* __restrict__ emb,
                             float* __restrict__ x) {
    int idx = blockIdx.x * blockDim.x + threadIdx.x;   // NT*ND threads
    int t = idx >> 10;
    int d = idx & 1023;
    int s = src[t];
    s = s < 0 ? 0 : (s > NV - 1 ? NV - 1 : s);
    x[idx] = emb[(size_t)s * ND + d] * 32.0f;
}

// ---------------------------------------------------------------------------
template<bool RELU>
__global__ void splitf_kernel(const float* __restrict__ src,
                              _Float16* __restrict__ dh, _Float16* __restrict__ dl, int n) {
    int i = blockIdx.x * blockDim.x + threadIdx.x;
    if (i >= n) return;
    float v = src[i];
    if (RELU) v = fmaxf(v, 0.f);
    _Float16 h = (_Float16)v;
    dh[i] = h;
    dl[i] = (_Float16)(v - (float)h);
}

// ---------------------------------------------------------------------------
// Transpose+split: src fp32 [K][N] -> dst fp16 hi/lo [N][K]
__global__ __launch_bounds__(256) void wtconvh_kernel(
    const float* __restrict__ src, _Float16* __restrict__ dh, _Float16* __restrict__ dl,
    int K, int N)
{
    __shared__ float tile[32][33];
    int n0 = blockIdx.x * 32, k0 = blockIdx.y * 32;
    int tx = threadIdx.x & 31, ty = threadIdx.x >> 5;
#pragma unroll
    for (int i = 0; i < 4; ++i)
        tile[ty + 8 * i][tx] = src[(size_t)(k0 + ty + 8 * i) * N + n0 + tx];
    __syncthreads();
#pragma unroll
    for (int i = 0; i < 4; ++i) {
        float v = tile[tx][ty + 8 * i];
        _Float16 h = (_Float16)v;
        size_t idx = (size_t)(n0 + ty + 8 * i) * K + k0 + tx;
        dh[idx] = h;
        dl[idx] = (_Float16)(v - (float)h);
    }
}

// ---------------------------------------------------------------------------
// Transpose+convert: src fp32 [K][N] -> dst bf16 [N][K]  (post-gate path)
__global__ __launch_bounds__(256) void wtconv_kernel(
    const float* __restrict__ src, bf16* __restrict__ dst, int K, int N)
{
    __shared__ float tile[32][33];
    int n0 = blockIdx.x * 32, k0 = blockIdx.y * 32;
    int tx = threadIdx.x & 31, ty = threadIdx.x >> 5;
#pragma unroll
    for (int i = 0; i < 4; ++i)
        tile[ty + 8 * i][tx] = src[(size_t)(k0 + ty + 8 * i) * N + n0 + tx];
    __syncthreads();
#pragma unroll
    for (int i = 0; i < 4; ++i)
        dst[(size_t)(n0 + ty + 8 * i) * K + k0 + tx] = f2b(tile[tx][ty + 8 * i]);
}

__global__ void biaspack_kernel(const float* __restrict__ qb, const float* __restrict__ kb,
                                const float* __restrict__ vb, float* __restrict__ dst) {
    int i = blockIdx.x * 256 + threadIdx.x;   // 3072
    dst[i] = i < 1024 ? qb[i] : (i < 2048 ? kb[i - 1024] : vb[i - 2048]);
}

// ---------------------------------------------------------------------------
// Split-fp16 single-pass GEMM: C = (Ah+Al)@(Bh+Bl)^T + bias  (drops Al*Bl)
// 128x128 tile, BK=64, 64KB LDS (Ah|Al|Bh|Bl), 3 MFMA per fragment pair.
__global__ __launch_bounds__(256) void mmsplit_kernel(
    const _Float16* __restrict__ Ah, const _Float16* __restrict__ Al,
    const _Float16* __restrict__ Bh, const _Float16* __restrict__ Bl,
    const float* __restrict__ bias, float* __restrict__ C,
    int M, int N, int K)
{
    __shared__ char smem[65536];
    const int tid = threadIdx.x;
    const int lane = tid & 63, wave = tid >> 6;
    const int wm = wave >> 1, wn = wave & 1;
    const int bm = blockIdx.y * 128, bn = blockIdx.x * 128;
    const int l15 = lane & 15, l4 = lane >> 4;
    const int srow = tid >> 3;
    const int sc = tid & 7;

    f32x4 acc[4][4];
#pragma unroll
    for (int i = 0; i < 4; ++i)
#pragma unroll
        for (int j = 0; j < 4; ++j) acc[i][j] = 0.f;

    for (int k0 = 0; k0 < K; k0 += 64) {
#pragma unroll
        for (int p = 0; p < 4; ++p) {
            int row = p * 32 + srow;
            int swc = (sc ^ (row & 7)) << 4;
            size_t ga = (size_t)(bm + row) * K + k0 + sc * 8;
            size_t gb = (size_t)(bn + row) * K + k0 + sc * 8;
            *(f16x8*)(smem +         row * 128 + swc) = *(const f16x8*)(Ah + ga);
            *(f16x8*)(smem + 16384 + row * 128 + swc) = *(const f16x8*)(Al + ga);
            *(f16x8*)(smem + 32768 + row * 128 + swc) = *(const f16x8*)(Bh + gb);
            *(f16x8*)(smem + 49152 + row * 128 + swc) = *(const f16x8*)(Bl + gb);
        }
        __syncthreads();
#pragma unroll
        for (int kk = 0; kk < 2; ++kk) {
            f16x8 afh[4], afl[4], bfh[4], bfl[4];
            int g = kk * 4 + l4;
#pragma unroll
            for (int mi = 0; mi < 4; ++mi) {
                int row = wm * 64 + mi * 16 + l15;
                int o = row * 128 + ((g ^ (row & 7)) << 4);
                afh[mi] = *(const f16x8*)(smem + o);
                afl[mi] = *(const f16x8*)(smem + 16384 + o);
            }
#pragma unroll
            for (int ni = 0; ni < 4; ++ni) {
                int row = wn * 64 + ni * 16 + l15;
                int o = row * 128 + ((g ^ (row & 7)) << 4);
                bfh[ni] = *(const f16x8*)(smem + 32768 + o);
                bfl[ni] = *(const f16x8*)(smem + 49152 + o);
            }
#pragma unroll
            for (int mi = 0; mi < 4; ++mi)
#pragma unroll
                for (int ni = 0; ni < 4; ++ni) {
                    acc[mi][ni] = __builtin_amdgcn_mfma_f32_16x16x32_f16(
                        afh[mi], bfh[ni], acc[mi][ni], 0, 0, 0);
                    acc[mi][ni] = __builtin_amdgcn_mfma_f32_16x16x32_f16(
                        afh[mi], bfl[ni], acc[mi][ni], 0, 0, 0);
                    acc[mi][ni] = __builtin_amdgcn_mfma_f32_16x16x32_f16(
                        afl[mi], bfh[ni], acc[mi][ni], 0, 0, 0);
                }
        }
        __syncthreads();
    }
#pragma unroll
    for (int ni = 0; ni < 4; ++ni) {
        int col = bn + wn * 64 + ni * 16 + l15;
        float bv = bias[col];
#pragma unroll
        for (int mi = 0; mi < 4; ++mi)
#pragma unroll
            for (int rr = 0; rr < 4; ++rr) {
                int row = bm + wm * 64 + mi * 16 + l4 * 4 + rr;
                C[(size_t)row * N + col] = acc[mi][ni][rr] + bv;
            }
    }
}

// ---------------------------------------------------------------------------
// bf16 MFMA GEMM (proven, post-gate). EPI: 0=f32, 1=bf16 relu, 3=f32 moe-acc
template<int EPI>
__global__ __launch_bounds__(256) void mm_kernel(
    const bf16* __restrict__ A, const bf16* __restrict__ BT,
    const float* __restrict__ bias, void* __restrict__ Cp,
    const float* __restrict__ rowscale, int M, int N, int K)
{
    __shared__ char smem[32768];
    const int tid = threadIdx.x;
    const int lane = tid & 63, wave = tid >> 6;
    const int wm = wave >> 1, wn = wave & 1;
    const int bm = blockIdx.y * 128, bn = blockIdx.x * 128;
    const int l15 = lane & 15, l4 = lane >> 4;
    const int srow = tid >> 3;
    const int sc = tid & 7;

    f32x4 acc[4][4];
#pragma unroll
    for (int i = 0; i < 4; ++i)
#pragma unroll
        for (int j = 0; j < 4; ++j) acc[i][j] = 0.f;

    for (int k0 = 0; k0 < K; k0 += 64) {
#pragma unroll
        for (int p = 0; p < 4; ++p) {
            int row = p * 32 + srow;
            int swc = (sc ^ (row & 7)) << 4;
            bf16x8 av = *(const bf16x8*)(A + (size_t)(bm + row) * K + k0 + sc * 8);
            bf16x8 bv = *(const bf16x8*)(BT + (size_t)(bn + row) * K + k0 + sc * 8);
            *(bf16x8*)(smem + row * 128 + swc) = av;
            *(bf16x8*)(smem + 16384 + row * 128 + swc) = bv;
        }
        __syncthreads();
#pragma unroll
        for (int kk = 0; kk < 2; ++kk) {
            bf16x8 af[4], bfv[4];
            int g = kk * 4 + l4;
#pragma unroll
            for (int mi = 0; mi < 4; ++mi) {
                int row = wm * 64 + mi * 16 + l15;
                af[mi] = *(const bf16x8*)(smem + row * 128 + ((g ^ (row & 7)) << 4));
            }
#pragma unroll
            for (int ni = 0; ni < 4; ++ni) {
                int row = wn * 64 + ni * 16 + l15;
                bfv[ni] = *(const bf16x8*)(smem + 16384 + row * 128 + ((g ^ (row & 7)) << 4));
            }
#pragma unroll
            for (int mi = 0; mi < 4; ++mi)
#pragma unroll
                for (int ni = 0; ni < 4; ++ni)
                    acc[mi][ni] = __builtin_amdgcn_mfma_f32_16x16x32_bf16(
                        af[mi], bfv[ni], acc[mi][ni], 0, 0, 0);
        }
        __syncthreads();
    }
#pragma unroll
    for (int ni = 0; ni < 4; ++ni) {
        int col = bn + wn * 64 + ni * 16 + l15;
        float bv = bias[col];
#pragma unroll
        for (int mi = 0; mi < 4; ++mi) {
#pragma unroll
            for (int rr = 0; rr < 4; ++rr) {
                int row = bm + wm * 64 + mi * 16 + l4 * 4 + rr;
                float v = acc[mi][ni][rr] + bv;
                if (EPI == 1) v = fmaxf(v, 0.f);
                if (EPI == 0)
                    ((float*)Cp)[(size_t)row * N + col] = v;
                else if (EPI == 3)
                    ((float*)Cp)[(size_t)row * N + col] += rowscale[(size_t)row * 8] * v;
                else
                    ((bf16*)Cp)[(size_t)row * N + col] = f2b(v);
            }
        }
    }
}

// ---------------------------------------------------------------------------
// RoPE + head-pack split: qkv fp32 [T][3072] ->
//   Qh/Ql,Kh/Kl [bh][s][64] fp16 (Q pre-scaled by 0.125), VTh/VTl [bh][64][1024]
__global__ __launch_bounds__(256) void ropehs_kernel(
    const float* __restrict__ qkv, const float* __restrict__ c, const float* __restrict__ sn,
    _Float16* __restrict__ Qh, _Float16* __restrict__ Ql,
    _Float16* __restrict__ Kh, _Float16* __restrict__ Kl,
    _Float16* __restrict__ VTh, _Float16* __restrict__ VTl)
{
    int st = blockIdx.x, bh = blockIdx.y;
    int b = bh >> 4, h = bh & 15;
    int s0 = st * 64;
    int tid = threadIdx.x;
#pragma unroll
    for (int it = 0; it < 8; ++it) {
        int idx = tid + 256 * it;       // 64 s x 32 j
        int sl = idx >> 5, j = idx & 31;
        int s = s0 + sl;
        size_t t = (size_t)b * NS + s;
        float cv = c[s * 32 + j], sv = sn[s * 32 + j];
        const float* base = qkv + t * 3072 + h * 64;
        float q1 = base[j], q2 = base[32 + j];
        float k1 = base[1024 + j], k2 = base[1024 + 32 + j];
        float qr1 = (q1 * cv - q2 * sv) * 0.125f;
        float qr2 = (q2 * cv + q1 * sv) * 0.125f;
        float kr1 = k1 * cv - k2 * sv;
        float kr2 = k2 * cv + k1 * sv;
        size_t o = (size_t)bh * 65536 + (size_t)s * 64;
        _Float16 hh1 = (_Float16)qr1, hh2 = (_Float16)qr2;
        Qh[o + j] = hh1;      Ql[o + j] = (_Float16)(qr1 - (float)hh1);
        Qh[o + 32 + j] = hh2; Ql[o + 32 + j] = (_Float16)(qr2 - (float)hh2);
        _Float16 kh1 = (_Float16)kr1, kh2 = (_Float16)kr2;
        Kh[o + j] = kh1;      Kl[o + j] = (_Float16)(kr1 - (float)kh1);
        Kh[o + 32 + j] = kh2; Kl[o + 32 + j] = (_Float16)(kr2 - (float)kh2);
    }
    __shared__ float vt[64][65];
    int dl = tid & 63, sq = tid >> 6;
#pragma unroll
    for (int i = 0; i < 16; ++i) {
        int sl = sq + 4 * i;
        size_t t = (size_t)b * NS + s0 + sl;
        vt[sl][dl] = qkv[t * 3072 + 2048 + h * 64 + dl];
    }
    __syncthreads();
#pragma unroll
    for (int i = 0; i < 16; ++i) {
        int d = sq + 4 * i;
        float v = vt[dl][d];
        _Float16 hv = (_Float16)v;
        size_t o = (size_t)bh * 65536 + (size_t)d * 1024 + s0 + dl;
        VTh[o] = hv;
        VTl[o] = (_Float16)(v - (float)hv);
    }
}

// ---------------------------------------------------------------------------
// Scores: S[bh][q][k] = Qh.Kh + Qh.Kl + Ql.Kh  (0.125 pre-folded), fp32 out.
__global__ __launch_bounds__(256) void scores_kernel(
    const _Float16* __restrict__ Qh, const _Float16* __restrict__ Ql,
    const _Float16* __restrict__ Kh, const _Float16* __restrict__ Kl,
    float* __restrict__ S)
{
    int bh = blockIdx.z;
    int q0 = blockIdx.y * 128, k0 = blockIdx.x * 128;
    int lane = threadIdx.x & 63, wave = threadIdx.x >> 6;
    int wm = wave >> 1, wn = wave & 1;
    int l15 = lane & 15, l4 = lane >> 4;
    size_t hb_ = (size_t)bh * 65536;
    f32x4 acc[4][4];
#pragma unroll
    for (int i = 0; i < 4; ++i)
#pragma unroll
        for (int j = 0; j < 4; ++j) acc[i][j] = 0.f;
#pragma unroll
    for (int kk = 0; kk < 2; ++kk) {
        f16x8 ah[4], al[4], bh2[4], bl[4];
#pragma unroll
        for (int mi = 0; mi < 4; ++mi) {
            size_t o = hb_ + (size_t)(q0 + wm * 64 + mi * 16 + l15) * 64 + kk * 32 + l4 * 8;
            ah[mi] = *(const f16x8*)(Qh + o);
            al[mi] = *(const f16x8*)(Ql + o);
        }
#pragma unroll
        for (int ni = 0; ni < 4; ++ni) {
            size_t o = hb_ + (size_t)(k0 + wn * 64 + ni * 16 + l15) * 64 + kk * 32 + l4 * 8;
            bh2[ni] = *(const f16x8*)(Kh + o);
            bl[ni]  = *(const f16x8*)(Kl + o);
        }
#pragma unroll
        for (int mi = 0; mi < 4; ++mi)
#pragma unroll
            for (int ni = 0; ni < 4; ++ni) {
                acc[mi][ni] = __builtin_amdgcn_mfma_f32_16x16x32_f16(ah[mi], bh2[ni], acc[mi][ni], 0, 0, 0);
                acc[mi][ni] = __builtin_amdgcn_mfma_f32_16x16x32_f16(ah[mi], bl[ni],  acc[mi][ni], 0, 0, 0);
                acc[mi][ni] = __builtin_amdgcn_mfma_f32_16x16x32_f16(al[mi], bh2[ni], acc[mi][ni], 0, 0, 0);
            }
    }
    float* Sb = S + (size_t)bh * 1048576;
#pragma unroll
    for (int mi = 0; mi < 4; ++mi)
#pragma unroll
        for (int ni = 0; ni < 4; ++ni)
#pragma unroll
            for (int rr = 0; rr < 4; ++rr)
                Sb[(size_t)(q0 + wm * 64 + mi * 16 + l4 * 4 + rr) * 1024 + k0 + wn * 64 + ni * 16 + l15] =
                    acc[mi][ni][rr];
}

// ---------------------------------------------------------------------------
// Row softmax over fp32 S, writing P back IN-PLACE as packed fp16 hi|lo:
// row bytes [0,2048)=Ph halfs, [2048,4096)=Pl halfs. 1 wave per row.
__global__ __launch_bounds__(256) void softmaxp_kernel(float* __restrict__ S) {
    int row = blockIdx.x * 4 + (threadIdx.x >> 6);   // 32768 rows
    int lane = threadIdx.x & 63;
    float* Srow = S + (size_t)row * 1024;
    float f[16];
#pragma unroll
    for (int i = 0; i < 4; ++i) {
        float4 v = *(const float4*)(Srow + lane * 16 + i * 4);
        f[i * 4 + 0] = v.x; f[i * 4 + 1] = v.y; f[i * 4 + 2] = v.z; f[i * 4 + 3] = v.w;
    }
    float m = -1e30f;
#pragma unroll
    for (int j = 0; j < 16; ++j) m = fmaxf(m, f[j]);
#pragma unroll
    for (int off = 32; off; off >>= 1) m = fmaxf(m, __shfl_xor(m, off));
    float s = 0.f;
#pragma unroll
    for (int j = 0; j < 16; ++j) { f[j] = __expf(f[j] - m); s += f[j]; }
#pragma unroll
    for (int off = 32; off; off >>= 1) s += __shfl_xor(s, off);
    float inv = 1.f / s;
    f16x8 ph[2], pl[2];
#pragma unroll
    for (int j = 0; j < 16; ++j) {
        float p = f[j] * inv;
        _Float16 h = (_Float16)p;
        ph[j >> 3][j & 7] = h;
        pl[j >> 3][j & 7] = (_Float16)(p - (float)h);
    }
    _Float16* Pr = (_Float16*)Srow;
    *(f16x8*)(Pr + lane * 16) = ph[0];
    *(f16x8*)(Pr + lane * 16 + 8) = ph[1];
    *(f16x8*)(Pr + 1024 + lane * 16) = pl[0];
    *(f16x8*)(Pr + 1024 + lane * 16 + 8) = pl[1];
}

// ---------------------------------------------------------------------------
// PV: O = P @ V via 3-term split MFMA vs transposed V. Tile 64q x 64d.
// Writes oh/ol fp16 [T][1024] directly.
__global__ __launch_bounds__(256) void pv_kernel(
    const float* __restrict__ Sp,
    const _Float16* __restrict__ VTh, const _Float16* __restrict__ VTl,
    _Float16* __restrict__ oh, _Float16* __restrict__ ol)
{
    int q0 = blockIdx.x * 64;          // 16 tiles
    int bh = blockIdx.y;
    int b = bh >> 4, h = bh & 15;
    int lane = threadIdx.x & 63, wave = threadIdx.x >> 6;
    int wm = wave >> 1, wn = wave & 1;
    int l15 = lane & 15, l4 = lane >> 4;
    const _Float16* Pb = (const _Float16*)(Sp + (size_t)bh * 1048576);  // rows of 2048 halfs
    size_t vb_ = (size_t)bh * 65536;
    f32x4 acc[2][2];
    acc[0][0] = 0.f; acc[0][1] = 0.f; acc[1][0] = 0.f; acc[1][1] = 0.f;
    for (int kv = 0; kv < 1024; kv += 32) {
        f16x8 ah[2], al[2], bh2[2], bl[2];
#pragma unroll
        for (int mi = 0; mi < 2; ++mi) {
            const _Float16* pr = Pb + (size_t)(q0 + wm * 32 + mi * 16 + l15) * 2048 + kv + l4 * 8;
            ah[mi] = *(const f16x8*)pr;
            al[mi] = *(const f16x8*)(pr + 1024);
        }
#pragma unroll
        for (int ni = 0; ni < 2; ++ni) {
            size_t o = vb_ + (size_t)(wn * 32 + ni * 16 + l15) * 1024 + kv + l4 * 8;
            bh2[ni] = *(const f16x8*)(VTh + o);
            bl[ni]  = *(const f16x8*)(VTl + o);
        }
#pragma unroll
        for (int mi = 0; mi < 2; ++mi)
#pragma unroll
            for (int ni = 0; ni < 2; ++ni) {
                acc[mi][ni] = __builtin_amdgcn_mfma_f32_16x16x32_f16(ah[mi], bh2[ni], acc[mi][ni], 0, 0, 0);
                acc[mi][ni] = __builtin_amdgcn_mfma_f32_16x16x32_f16(ah[mi], bl[ni],  acc[mi][ni], 0, 0, 0);
                acc[mi][ni] = __builtin_amdgcn_mfma_f32_16x16x32_f16(al[mi], bh2[ni], acc[mi][ni], 0, 0, 0);
            }
    }
#pragma unroll
    for (int mi = 0; mi < 2; ++mi)
#pragma unroll
        for (int ni = 0; ni < 2; ++ni)
#pragma unroll
            for (int rr = 0; rr < 4; ++rr) {
                int qrow = q0 + wm * 32 + mi * 16 + l4 * 4 + rr;
                int d = wn * 32 + ni * 16 + l15;
                size_t idx = ((size_t)(b * NS + qrow)) * ND + h * 64 + d;
                float v = acc[mi][ni][rr];
                _Float16 hv = (_Float16)v;
                oh[idx] = hv;
                ol[idx] = (_Float16)(v - (float)hv);
            }
}

// ---------------------------------------------------------------------------
__global__ __launch_bounds__(256) void ln_kernel(
    const float* __restrict__ res, const float* __restrict__ y,
    const float* __restrict__ g, const float* __restrict__ b,
    float* __restrict__ outp)
{
    int t = blockIdx.x, tid = threadIdx.x;
    size_t base = (size_t)t * ND;
    float v[4];
    float s = 0.f, s2 = 0.f;
#pragma unroll
    for (int i = 0; i < 4; ++i) {
        int d = tid + 256 * i;
        float val = y[base + d];
        if (res) val += res[base + d];
        v[i] = val;
        s += val;
        s2 += val * val;
    }
    for (int off = 32; off; off >>= 1) {
        s  += __shfl_xor(s, off);
        s2 += __shfl_xor(s2, off);
    }
    __shared__ float rs[4], rs2[4];
    int wave = tid >> 6, lane = tid & 63;
    if (!lane) { rs[wave] = s; rs2[wave] = s2; }
    __syncthreads();
    s = rs[0] + rs[1] + rs[2] + rs[3];
    s2 = rs2[0] + rs2[1] + rs2[2] + rs2[3];
    float mu = s / ND;
    float var = s2 / ND - mu * mu;
    float rstd = rsqrtf(var + 1e-5f);
#pragma unroll
    for (int i = 0; i < 4; ++i) {
        int d = tid + 256 * i;
        outp[base + d] = (v[i] - mu) * rstd * g[d] + b[d];
    }
}

// ---------------------------------------------------------------------------
__global__ __launch_bounds__(256) void gate_kernel(
    const float* __restrict__ x, const float* __restrict__ gw,
    const float* __restrict__ gb, float* __restrict__ we)
{
    int t = blockIdx.x, tid = threadIdx.x;
    float acc[8] = {};
#pragma unroll
    for (int i = 0; i < 4; ++i) {
        int d = tid * 4 + i;
        float xv = x[(size_t)t * ND + d];
#pragma unroll
        for (int e = 0; e < 8; ++e) acc[e] += xv * gw[d * 8 + e];
    }
    for (int off = 32; off; off >>= 1)
#pragma unroll
        for (int e = 0; e < 8; ++e) acc[e] += __shfl_xor(acc[e], off);
    __shared__ float red[4][8];
    int wave = tid >> 6, lane = tid & 63;
    if (!lane)
#pragma unroll
        for (int e = 0; e < 8; ++e) red[wave][e] = acc[e];
    __syncthreads();
    if (tid == 0) {
        float lg[8];
#pragma unroll
        for (int e = 0; e < 8; ++e)
            lg[e] = red[0][e] + red[1][e] + red[2][e] + red[3][e] + gb[e];
        int i1 = 0;
        for (int e = 1; e < 8; ++e) if (lg[e] > lg[i1]) i1 = e;
        int i2 = -1;
        for (int e = 0; e < 8; ++e) if (e != i1 && (i2 < 0 || lg[e] > lg[i2])) i2 = e;
        float e2 = __expf(lg[i2] - lg[i1]);
        float denom = 1.f + e2;
#pragma unroll
        for (int e = 0; e < 8; ++e) we[t * 8 + e] = 0.f;
        we[t * 8 + i1] = 1.f / denom;
        we[t * 8 + i2] = e2 / denom;
    }
}

__global__ void zero_kernel(float* __restrict__ p, int n) {
    int i = blockIdx.x * blockDim.x + threadIdx.x;
    if (i < n) p[i] = 0.f;
}

__global__ void cast_kernel(const float* __restrict__ src, bf16* __restrict__ dst, int n) {
    int i = blockIdx.x * blockDim.x + threadIdx.x;
    if (i < n) dst[i] = f2b(src[i]);
}

// ---------------------------------------------------------------------------
extern "C" void kernel_launch(void* const* d_in, const int* in_sizes, int n_in,
                              void* d_out, int out_size, void* d_ws, size_t ws_size,
                              hipStream_t stream) {
    (void)in_sizes; (void)n_in; (void)out_size; (void)ws_size;
    const int*   src  = (const int*)  d_in[0];
    const float* emb  = (const float*)d_in[1];
    const float* qw   = (const float*)d_in[2];
    const float* qb   = (const float*)d_in[3];
    const float* kw   = (const float*)d_in[4];
    const float* kb   = (const float*)d_in[5];
    const float* vw   = (const float*)d_in[6];
    const float* vb   = (const float*)d_in[7];
    const float* ow   = (const float*)d_in[8];
    const float* ob   = (const float*)d_in[9];
    const float* f1w  = (const float*)d_in[10];
    const float* f1b  = (const float*)d_in[11];
    const float* f2w  = (const float*)d_in[12];
    const float* f2b_ = (const float*)d_in[13];
    const float* ln1g = (const float*)d_in[14];
    const float* ln1b = (const float*)d_in[15];
    const float* ln2g = (const float*)d_in[16];
    const float* ln2b = (const float*)d_in[17];
    const float* gw   = (const float*)d_in[18];
    const float* gb   = (const float*)d_in[19];
    const float* ew1  = (const float*)d_in[20];
    const float* eb1  = (const float*)d_in[21];
    const float* ew2  = (const float*)d_in[22];
    const float* eb2  = (const float*)d_in[23];
    const float* flng = (const float*)d_in[24];
    const float* flnb = (const float*)d_in[25];
    const float* outw = (const float*)d_in[26];
    const float* outb = (const float*)d_in[27];
    float* out = (float*)d_out;

    char* w = (char*)d_ws;
    size_t off = 0;
    auto alloc = [&](size_t bytes) -> char* {
        size_t cur = (off + 255) & ~(size_t)255;
        off = cur + bytes;
        return w + cur;
    };

    float* xbuf   = (float*)alloc((size_t)NT * ND * 4);       // 8MB
    float* qkvbuf = (float*)alloc((size_t)NT * 3072 * 4);     // 24MB
    float* tbuf   = (float*)alloc((size_t)NT * ND * 4);       // 8MB
    float* macc   = (float*)alloc((size_t)NT * ND * 4);       // 8MB
    _Float16* xh  = (_Float16*)alloc((size_t)NT * ND * 2);
    _Float16* xl  = (_Float16*)alloc((size_t)NT * ND * 2);
    _Float16* oh  = (_Float16*)alloc((size_t)NT * ND * 2);
    _Float16* ol  = (_Float16*)alloc((size_t)NT * ND * 2);
    _Float16* wqkvh = (_Float16*)alloc((size_t)3072 * ND * 2);   // 6MB
    _Float16* wqkvl = (_Float16*)alloc((size_t)3072 * ND * 2);
    _Float16* woh = (_Float16*)alloc((size_t)ND * ND * 2);
    _Float16* wol = (_Float16*)alloc((size_t)ND * ND * 2);
    _Float16* w1h = (_Float16*)alloc((size_t)ND * NDFF * 2);
    _Float16* w1l = (_Float16*)alloc((size_t)ND * NDFF * 2);
    _Float16* w2h = (_Float16*)alloc((size_t)ND * NDFF * 2);
    _Float16* w2l = (_Float16*)alloc((size_t)ND * NDFF * 2);
    _Float16* Qhh = (_Float16*)alloc((size_t)32 * NS * 64 * 2);  // 4MB each
    _Float16* Qll = (_Float16*)alloc((size_t)32 * NS * 64 * 2);
    _Float16* Khh = (_Float16*)alloc((size_t)32 * NS * 64 * 2);
    _Float16* Kll = (_Float16*)alloc((size_t)32 * NS * 64 * 2);
    _Float16* VTh = (_Float16*)alloc((size_t)32 * 64 * NS * 2);
    _Float16* VTl = (_Float16*)alloc((size_t)32 * 64 * NS * 2);
    float* webuf  = (float*)alloc((size_t)NT * NE * 4);
    float* cbuf   = (float*)alloc((size_t)NS * 32 * 4);
    float* snbuf  = (float*)alloc((size_t)NS * 32 * 4);
    float* qkvbias = (float*)alloc(3072 * 4);
    char*  Sbig   = alloc(134217728);                          // 128MB scores / multi-alias

    float* Sbuf = (float*)Sbig;                    // attention phase
    float* hbuf = (float*)Sbig;                    // FFN phase fp32 [0,32MB)
    _Float16* hh = (_Float16*)(Sbig + 33554432);   // [32,48MB)
    _Float16* hl = (_Float16*)(Sbig + 50331648);   // [48,64MB)
    bf16* outwt = (bf16*)Sbig;                     // post-gate [0,62.5MB)
    bf16* hb    = (bf16*)(Sbig + 67108864);        // [64,80MB)
    bf16* e1t   = (bf16*)(Sbig + 83886080);        // [80,88MB)
    bf16* e2t   = (bf16*)(Sbig + 92274688);        // [88,96MB)
    bf16* xb    = (bf16*)(Sbig + 100663296);       // [96,100MB)
    bf16* lnout = (bf16*)(Sbig + 104857600);       // [100,104MB)

    const int NX = NT * ND;
    yarn_kernel<<<(NS * 32) / 256, 256, 0, stream>>>(cbuf, snbuf);
    embed_kernel<<<NX / 256, 256, 0, stream>>>(src, emb, xbuf);
    splitf_kernel<false><<<NX / 256, 256, 0, stream>>>(xbuf, xh, xl, NX);

    for (int l = 0; l < NL; ++l) {
        wtconvh_kernel<<<dim3(32, 32), 256, 0, stream>>>(qw + (size_t)l * 1048576, wqkvh, wqkvl, 1024, 1024);
        wtconvh_kernel<<<dim3(32, 32), 256, 0, stream>>>(kw + (size_t)l * 1048576, wqkvh + 1048576, wqkvl + 1048576, 1024, 1024);
        wtconvh_kernel<<<dim3(32, 32), 256, 0, stream>>>(vw + (size_t)l * 1048576, wqkvh + 2097152, wqkvl + 2097152, 1024, 1024);
        wtconvh_kernel<<<dim3(32, 32), 256, 0, stream>>>(ow + (size_t)l * 1048576, woh, wol, 1024, 1024);
        wtconvh_kernel<<<dim3(128, 32), 256, 0, stream>>>(f1w + (size_t)l * 4194304, w1h, w1l, 1024, 4096);
        wtconvh_kernel<<<dim3(32, 128), 256, 0, stream>>>(f2w + (size_t)l * 4194304, w2h, w2l, 4096, 1024);
        biaspack_kernel<<<12, 256, 0, stream>>>(qb + l * 1024, kb + l * 1024, vb + l * 1024, qkvbias);

        // fused QKV projection (split-fp16, fp32 out)
        mmsplit_kernel<<<dim3(24, 16), 256, 0, stream>>>(xh, xl, wqkvh, wqkvl, qkvbias, qkvbuf, NT, 3072, 1024);
        // rope + head-pack + V transpose (all split-fp16)
        ropehs_kernel<<<dim3(16, 32), 256, 0, stream>>>(qkvbuf, cbuf, snbuf, Qhh, Qll, Khh, Kll, VTh, VTl);
        // attention: MFMA scores -> softmax -> MFMA PV
        scores_kernel<<<dim3(8, 8, 32), 256, 0, stream>>>(Qhh, Qll, Khh, Kll, Sbuf);
        softmaxp_kernel<<<8192, 256, 0, stream>>>(Sbuf);
        pv_kernel<<<dim3(16, 32), 256, 0, stream>>>(Sbuf, VTh, VTl, oh, ol);
        // O projection
        mmsplit_kernel<<<dim3(8, 16), 256, 0, stream>>>(oh, ol, woh, wol, ob + l * 1024, tbuf, NT, 1024, 1024);
        ln_kernel<<<NT, 256, 0, stream>>>(xbuf, tbuf, ln1g + l * 1024, ln1b + l * 1024, xbuf);
        splitf_kernel<false><<<NX / 256, 256, 0, stream>>>(xbuf, xh, xl, NX);
        // FFN
        mmsplit_kernel<<<dim3(32, 16), 256, 0, stream>>>(xh, xl, w1h, w1l, f1b + l * 4096, hbuf, NT, 4096, 1024);
        splitf_kernel<true><<<(NT * NDFF) / 256, 256, 0, stream>>>(hbuf, hh, hl, NT * NDFF);
        mmsplit_kernel<<<dim3(8, 16), 256, 0, stream>>>(hh, hl, w2h, w2l, f2b_ + l * 1024, tbuf, NT, 1024, 4096);
        ln_kernel<<<NT, 256, 0, stream>>>(xbuf, tbuf, ln2g + l * 1024, ln2b + l * 1024, xbuf);
        splitf_kernel<false><<<NX / 256, 256, 0, stream>>>(xbuf, xh, xl, NX);
    }

    // Gate on exact fp32 x
    gate_kernel<<<NT, 256, 0, stream>>>(xbuf, gw, gb, webuf);

    // Post-gate: bf16 MFMA (round-5 proven)
    cast_kernel<<<NX / 256, 256, 0, stream>>>(xbuf, xb, NX);
    zero_kernel<<<NX / 256, 256, 0, stream>>>(macc, NX);
    wtconv_kernel<<<dim3(1000, 32), 256, 0, stream>>>(outw, outwt, 1024, 32000);
    for (int e = 0; e < NE; ++e) {
        wtconv_kernel<<<dim3(128, 32), 256, 0, stream>>>(ew1 + (size_t)e * 4194304, e1t, 1024, 4096);
        wtconv_kernel<<<dim3(32, 128), 256, 0, stream>>>(ew2 + (size_t)e * 4194304, e2t, 4096, 1024);
        mm_kernel<1><<<dim3(32, 16), 256, 0, stream>>>(xb, e1t, eb1 + e * 4096, hb, nullptr, NT, 4096, 1024);
        mm_kernel<3><<<dim3(8, 16), 256, 0, stream>>>(hb, e2t, eb2 + e * 1024, macc, webuf + e, NT, 1024, 4096);
    }
    ln_kernel<<<NT, 256, 0, stream>>>(nullptr, macc, flng, flnb, tbuf);
    cast_kernel<<<NX / 256, 256, 0, stream>>>(tbuf, lnout, NX);
    mm_kernel<0><<<dim3(250, 16), 256, 0, stream>>>(lnout, outwt, outb, out, nullptr, NT, NV, 1024);
}